// Round 1
// baseline (1872.501 us; speedup 1.0000x reference)
//
#include <hip/hip_runtime.h>
#include <math.h>

#define B_ 2
#define T_ 512
#define D_ 1024
#define H_ 16
#define R_ 32
#define DH 64
#define BT_ (B_*T_)
#define BH_ (B_*H_)

// ======================= generic 64x64 fp32 GEMM =======================
// MODE 0: C[M,N] row-major.  MODE 1: scatter output to [B,H,T,dh] (v-transpose).
template<int MODE>
__global__ __launch_bounds__(256) void gemm64(const float* __restrict__ A,
                                              const float* __restrict__ Bm,
                                              float* __restrict__ C,
                                              int M, int N, int K) {
  __shared__ float As[16][64];   // [k][m]
  __shared__ float Bs[16][64];   // [k][n]
  const int bm = blockIdx.y * 64, bn = blockIdx.x * 64;
  const int tid = threadIdx.x;
  const int tm = (tid >> 4) << 2, tn = (tid & 15) << 2;
  const int ar = tid >> 2, ac = (tid & 3) << 2;
  const int br = tid >> 4, bc = (tid & 15) << 2;
  float acc[4][4] = {};
  const float* Ap = A + (size_t)(bm + ar) * K + ac;
  const float* Bp = Bm + (size_t)br * N + bn + bc;
  for (int k0 = 0; k0 < K; k0 += 16) {
    float4 av = *(const float4*)(Ap + k0);
    float4 bv = *(const float4*)(Bp + (size_t)k0 * N);
    __syncthreads();
    As[ac + 0][ar] = av.x; As[ac + 1][ar] = av.y; As[ac + 2][ar] = av.z; As[ac + 3][ar] = av.w;
    *(float4*)&Bs[br][bc] = bv;
    __syncthreads();
#pragma unroll
    for (int kk = 0; kk < 16; ++kk) {
      float4 a = *(const float4*)&As[kk][tm];
      float4 b = *(const float4*)&Bs[kk][tn];
      acc[0][0] += a.x * b.x; acc[0][1] += a.x * b.y; acc[0][2] += a.x * b.z; acc[0][3] += a.x * b.w;
      acc[1][0] += a.y * b.x; acc[1][1] += a.y * b.y; acc[1][2] += a.y * b.z; acc[1][3] += a.y * b.w;
      acc[2][0] += a.z * b.x; acc[2][1] += a.z * b.y; acc[2][2] += a.z * b.z; acc[2][3] += a.z * b.w;
      acc[3][0] += a.w * b.x; acc[3][1] += a.w * b.y; acc[3][2] += a.w * b.z; acc[3][3] += a.w * b.w;
    }
  }
  if (MODE == 0) {
#pragma unroll
    for (int ii = 0; ii < 4; ++ii) {
      float4 r; r.x = acc[ii][0]; r.y = acc[ii][1]; r.z = acc[ii][2]; r.w = acc[ii][3];
      *(float4*)&C[(size_t)(bm + tm + ii) * N + bn + tn] = r;
    }
  } else {
#pragma unroll
    for (int ii = 0; ii < 4; ++ii) {
      int m = bm + tm + ii; int b = m / T_, t = m - b * T_;
#pragma unroll
      for (int jj = 0; jj < 4; ++jj) {
        int n = bn + tn + jj; int h = n >> 6, dd = n & 63;
        C[(((size_t)(b * H_ + h)) * T_ + t) * DH + dd] = acc[ii][jj];
      }
    }
  }
}

// ======================= small projections: wlow, beta, g =======================
// one block per (b,t) row; 64 threads; outputs: wlow[bt][32], beta[bh][t], g[bh][t]
__global__ __launch_bounds__(64) void proj_small(const float* __restrict__ x,
                                                 const float* __restrict__ wA,
                                                 const float* __restrict__ bw,
                                                 const float* __restrict__ gw,
                                                 const float* __restrict__ gb,
                                                 float* __restrict__ wlow,
                                                 float* __restrict__ beta,
                                                 float* __restrict__ gout) {
  int bt = blockIdx.x, b = bt / T_, t = bt - b * T_;
  __shared__ float xs[D_];
  int tid = threadIdx.x;
  for (int i = tid * 4; i < D_; i += 256) {
    *(float4*)&xs[i] = *(const float4*)&x[(size_t)bt * D_ + i];
  }
  __syncthreads();
  if (tid < R_) {
    float a = 0.f;
    for (int i = 0; i < D_; ++i) a += xs[i] * wA[(size_t)i * R_ + tid];
    wlow[(size_t)bt * R_ + tid] = a;
  } else if (tid < R_ + H_) {
    int h = tid - R_;
    float a = 0.f;
    for (int i = 0; i < D_; ++i) a += xs[i] * bw[(size_t)i * H_ + h];
    beta[((size_t)(b * H_ + h)) * T_ + t] = 2.f / (1.f + expf(-a));
  } else {
    int h = tid - R_ - H_;
    float a = gb[h];
    for (int i = 0; i < D_; ++i) a += xs[i] * gw[(size_t)i * H_ + h];
    float mn = fminf(a, 0.f);                       // logsigmoid(a)
    gout[((size_t)(b * H_ + h)) * T_ + t] = mn - log1pf(expf(-fabsf(a)));
  }
}

// ======================= inclusive cumsum over T per (b,h) =======================
__global__ __launch_bounds__(512) void cumsum_k(float* __restrict__ G) {
  __shared__ float s[T_];
  int bh = blockIdx.x, t = threadIdx.x;
  s[t] = G[(size_t)bh * T_ + t];
  __syncthreads();
  for (int off = 1; off < T_; off <<= 1) {
    float v = (t >= off) ? s[t - off] : 0.f;
    __syncthreads();
    s[t] += v;
    __syncthreads();
  }
  G[(size_t)bh * T_ + t] = s[t];
}

// ======================= w: low-rank expand + conv3 + silu + unit-normalize ===========
// one block per (b,t); 1024 threads (one per D column); head == wave (d=64 == wave64)
__global__ __launch_bounds__(1024) void wdir_k(const float* __restrict__ wlow,
                                               const float* __restrict__ wB,
                                               const float* __restrict__ convw,
                                               float* __restrict__ wT) {
  int bt = blockIdx.x, b = bt / T_, t = bt - b * T_;
  __shared__ float wl[3][R_];
  int tid = threadIdx.x;
  if (tid < 3 * R_) {
    int row = tid / R_, r = tid - row * R_;
    int ts = t - row;
    wl[row][r] = (ts >= 0) ? wlow[(size_t)(b * T_ + ts) * R_ + r] : 0.f;
  }
  __syncthreads();
  float f0 = 0.f, f1 = 0.f, f2 = 0.f;
  for (int r = 0; r < R_; ++r) {
    float wb = wB[(size_t)r * D_ + tid];
    f0 += wl[0][r] * wb; f1 += wl[1][r] * wb; f2 += wl[2][r] * wb;
  }
  // w_new[t] = w[t-2]*cw0 + w[t-1]*cw1 + w[t]*cw2
  float y = f2 * convw[tid * 3 + 0] + f1 * convw[tid * 3 + 1] + f0 * convw[tid * 3 + 2];
  float s = y / (1.f + expf(-y));                       // silu
  float ss = s * s;
#pragma unroll
  for (int m = 32; m >= 1; m >>= 1) ss += __shfl_xor(ss, m);
  float outv = s * rsqrtf(ss + 1e-12f);
  int h = tid >> 6, dd = tid & 63;
  wT[(((size_t)(b * H_ + h)) * T_ + t) * DH + dd] = outv;
}

// ======================= rmsnorm q,k + transpose to [B,H,T,dh] =======================
__global__ __launch_bounds__(1024) void rmsT_k(const float* __restrict__ q,
                                               const float* __restrict__ k,
                                               const float* __restrict__ qnw,
                                               const float* __restrict__ knw,
                                               float* __restrict__ qT,
                                               float* __restrict__ kT) {
  int bt = blockIdx.x, b = bt / T_, t = bt - b * T_;
  int tid = threadIdx.x, h = tid >> 6, dd = tid & 63;
  float qv = q[(size_t)bt * D_ + tid];
  float kv = k[(size_t)bt * D_ + tid];
  float sq = qv * qv, sk = kv * kv;
#pragma unroll
  for (int m = 32; m >= 1; m >>= 1) { sq += __shfl_xor(sq, m); sk += __shfl_xor(sk, m); }
  float qs = qv * rsqrtf(sq * (1.f / DH) + 1e-5f) * qnw[dd];
  float ks = kv * rsqrtf(sk * (1.f / DH) + 1e-5f) * knw[dd];
  size_t o = (((size_t)(b * H_ + h)) * T_ + t) * DH + dd;
  qT[o] = qs;
  kT[o] = ks;
}

// ======================= UT/WY blocked triangular solve =======================
// A = L^{-1} Rhs, L = I + tril(C,-1), C[t,s] = (w_t.w_s) beta_s, Rhs = tril(W K^T,-1).
// Output Ab = beta_t * A[t,j].  Columns are independent -> grid (chunk=8, bh=32).
// WY recurrence: M[:,j] = sum_{s<t0} w_s * (beta A)[s,j]  (in LDS, rank-d).
__global__ __launch_bounds__(512) void solve_k(const float* __restrict__ wT,
                                               const float* __restrict__ kT,
                                               const float* __restrict__ beta,
                                               float* __restrict__ Ab) {
  int ch = blockIdx.x, bh = blockIdx.y;
  __shared__ float KshT[DH][65];   // [dd][j]
  __shared__ float MshT[DH][65];   // [dd][j]
  __shared__ float Wsh[DH][68];    // [r][dd]
  __shared__ float WshT[DH][65];   // [dd][r]
  __shared__ float Ash[DH][65];    // [r][j]
  __shared__ float Csh[DH][65];    // [r][s]
  __shared__ float bI[DH];
  const int tid = threadIdx.x, tx = tid & 63, ty = tid >> 6;   // ty in 0..7

  // load K columns of this chunk, transposed
  for (int it = 0; it < 2; ++it) {
    int f = tid + it * 512;
    int j = f >> 4, c4 = (f & 15) << 2;
    float4 v = *(const float4*)&kT[(((size_t)bh) * T_ + ch * 64 + j) * DH + c4];
    KshT[c4 + 0][j] = v.x; KshT[c4 + 1][j] = v.y; KshT[c4 + 2][j] = v.z; KshT[c4 + 3][j] = v.w;
  }
  for (int i = tid; i < DH * 65; i += 512) ((float*)MshT)[i] = 0.f;

  const int jg = ch * 64 + tx;
  for (int I = 0; I < 8; ++I) {
    const int t0 = I * 64;
    __syncthreads();                    // protect Wsh/Ash reuse
    for (int it = 0; it < 2; ++it) {
      int f = tid + it * 512;
      int r = f >> 4, c4 = (f & 15) << 2;
      float4 v = *(const float4*)&wT[(((size_t)bh) * T_ + t0 + r) * DH + c4];
      *(float4*)&Wsh[r][c4] = v;
      WshT[c4 + 0][r] = v.x; WshT[c4 + 1][r] = v.y; WshT[c4 + 2][r] = v.z; WshT[c4 + 3][r] = v.w;
    }
    if (tid < 64) bI[tid] = beta[(size_t)bh * T_ + t0 + tid];
    __syncthreads();

    // hoist (k_j - M[:,j]) into registers for this thread's column
    float km[DH];
#pragma unroll
    for (int dd = 0; dd < DH; ++dd) km[dd] = KshT[dd][tx] - MshT[dd][tx];

    // P[r][j] = mask(jg < t) * w_t . (k_j - M[:,j])
#pragma unroll
    for (int rr = 0; rr < 8; ++rr) {
      int r = ty * 8 + rr;
      float a = 0.f;
#pragma unroll
      for (int dd = 0; dd < DH; ++dd) a += Wsh[r][dd] * km[dd];
      Ash[r][tx] = (jg < t0 + r) ? a : 0.f;
    }
    // C[r][s] = (w_r.w_s) * beta_s, strictly lower
#pragma unroll
    for (int rr = 0; rr < 8; ++rr) {
      int r = ty * 8 + rr;
      float a = 0.f;
#pragma unroll
      for (int dd = 0; dd < DH; ++dd) a += Wsh[r][dd] * WshT[dd][tx];
      Csh[r][tx] = (tx < r) ? a * bI[tx] : 0.f;
    }
    __syncthreads();

    // in-block forward substitution (rank-1 update form)
    for (int r = 0; r < 63; ++r) {
      float arj = Ash[r][tx];
      for (int r2 = r + 1 + ty; r2 < 64; r2 += 8) Ash[r2][tx] -= Csh[r2][r] * arj;
      __syncthreads();
    }

    // scale rows by beta -> Ab = beta * A
#pragma unroll
    for (int rr = 0; rr < 8; ++rr) { int r = ty * 8 + rr; Ash[r][tx] *= bI[r]; }
    __syncthreads();

    // M[:,j] += sum_s w_s * (beta A)[s,j]
#pragma unroll
    for (int dq = 0; dq < 8; ++dq) {
      int dd = ty * 8 + dq;
      float a = MshT[dd][tx];
#pragma unroll
      for (int s = 0; s < 64; ++s) a += WshT[dd][s] * Ash[s][tx];
      MshT[dd][tx] = a;
    }
    // write out
#pragma unroll
    for (int rr = 0; rr < 8; ++rr) {
      int r = ty * 8 + rr;
      Ab[((size_t)bh * T_ + t0 + r) * T_ + ch * 64 + tx] = Ash[r][tx];
    }
  }
}

// ======================= S = Q K^T - tril(Q W^T) @ (beta A) =======================
// grid (jt, it, bh), 64x64 tile; qw tiles recomputed on the fly; skips jt>it tiles.
__global__ __launch_bounds__(256) void s_kernel(const float* __restrict__ qT,
                                                const float* __restrict__ kT,
                                                const float* __restrict__ wT,
                                                const float* __restrict__ Ab,
                                                float* __restrict__ S) {
  int jt = blockIdx.x, it = blockIdx.y, bh = blockIdx.z;
  if (jt > it) return;                           // masked by softmax; never read
  __shared__ float QsT[DH][65];  // [dd][i]
  __shared__ float WsT[DH][65];  // [dd][t]  (reused as [dd][j] for K)
  __shared__ float QWs[DH][65];  // [i][t]
  __shared__ float ABs[DH][68];  // [t][j]
  const int tid = threadIdx.x;
  const int tm = (tid >> 4) << 2, tn = (tid & 15) << 2;

  for (int l = 0; l < 4; ++l) {
    int f = tid + l * 256;
    int i = f >> 4, c4 = (f & 15) << 2;
    float4 v = *(const float4*)&qT[(((size_t)bh) * T_ + it * 64 + i) * DH + c4];
    QsT[c4 + 0][i] = v.x; QsT[c4 + 1][i] = v.y; QsT[c4 + 2][i] = v.z; QsT[c4 + 3][i] = v.w;
  }
  float accQW[4][4] = {};
  for (int c = 0; c < 8; ++c) {
    __syncthreads();
    for (int l = 0; l < 4; ++l) {
      int f = tid + l * 256;
      int r = f >> 4, c4 = (f & 15) << 2;
      float4 v = *(const float4*)&wT[(((size_t)bh) * T_ + c * 64 + r) * DH + c4];
      WsT[c4 + 0][r] = v.x; WsT[c4 + 1][r] = v.y; WsT[c4 + 2][r] = v.z; WsT[c4 + 3][r] = v.w;
      *(float4*)&ABs[r][c4] = *(const float4*)&Ab[((size_t)bh * T_ + c * 64 + r) * T_ + jt * 64 + c4];
    }
    __syncthreads();
    // qw tile: [i][t] = Q_i . w_t, mask t<=i
#pragma unroll
    for (int ii = 0; ii < 4; ++ii) {
#pragma unroll
      for (int jj = 0; jj < 4; ++jj) {
        float a = 0.f;
        for (int dd = 0; dd < DH; ++dd) a += QsT[dd][tm + ii] * WsT[dd][tn + jj];
        int tg = c * 64 + tn + jj, ig = it * 64 + tm + ii;
        QWs[tm + ii][tn + jj] = (tg <= ig) ? a : 0.f;
      }
    }
    __syncthreads();
    // acc += qw @ Ab
#pragma unroll
    for (int kk = 0; kk < 64; ++kk) {
      float a0 = QWs[tm + 0][kk], a1 = QWs[tm + 1][kk], a2 = QWs[tm + 2][kk], a3 = QWs[tm + 3][kk];
      float4 b = *(const float4*)&ABs[kk][tn];
      accQW[0][0] += a0 * b.x; accQW[0][1] += a0 * b.y; accQW[0][2] += a0 * b.z; accQW[0][3] += a0 * b.w;
      accQW[1][0] += a1 * b.x; accQW[1][1] += a1 * b.y; accQW[1][2] += a1 * b.z; accQW[1][3] += a1 * b.w;
      accQW[2][0] += a2 * b.x; accQW[2][1] += a2 * b.y; accQW[2][2] += a2 * b.z; accQW[2][3] += a2 * b.w;
      accQW[3][0] += a3 * b.x; accQW[3][1] += a3 * b.y; accQW[3][2] += a3 * b.z; accQW[3][3] += a3 * b.w;
    }
  }
  // + Q K^T term
  __syncthreads();
  for (int l = 0; l < 4; ++l) {
    int f = tid + l * 256;
    int j = f >> 4, c4 = (f & 15) << 2;
    float4 v = *(const float4*)&kT[(((size_t)bh) * T_ + jt * 64 + j) * DH + c4];
    WsT[c4 + 0][j] = v.x; WsT[c4 + 1][j] = v.y; WsT[c4 + 2][j] = v.z; WsT[c4 + 3][j] = v.w;
  }
  __syncthreads();
  float qk[4][4] = {};
  for (int dd = 0; dd < DH; ++dd) {
    float a0 = QsT[dd][tm + 0], a1 = QsT[dd][tm + 1], a2 = QsT[dd][tm + 2], a3 = QsT[dd][tm + 3];
    float b0 = WsT[dd][tn + 0], b1 = WsT[dd][tn + 1], b2 = WsT[dd][tn + 2], b3 = WsT[dd][tn + 3];
    qk[0][0] += a0 * b0; qk[0][1] += a0 * b1; qk[0][2] += a0 * b2; qk[0][3] += a0 * b3;
    qk[1][0] += a1 * b0; qk[1][1] += a1 * b1; qk[1][2] += a1 * b2; qk[1][3] += a1 * b3;
    qk[2][0] += a2 * b0; qk[2][1] += a2 * b1; qk[2][2] += a2 * b2; qk[2][3] += a2 * b3;
    qk[3][0] += a3 * b0; qk[3][1] += a3 * b1; qk[3][2] += a3 * b2; qk[3][3] += a3 * b3;
  }
#pragma unroll
  for (int ii = 0; ii < 4; ++ii)
#pragma unroll
    for (int jj = 0; jj < 4; ++jj)
      S[((size_t)bh * T_ + it * 64 + tm + ii) * T_ + jt * 64 + tn + jj] = qk[ii][jj] - accQW[ii][jj];
}

// ======================= softmax with gate-cumsum bias, causal =======================
__global__ __launch_bounds__(64) void softmax_k(float* __restrict__ S, const float* __restrict__ G) {
  int i = blockIdx.x, bh = blockIdx.y;
  int lane = threadIdx.x;
  const float Gi = G[(size_t)bh * T_ + i];
  float* row = S + ((size_t)bh * T_ + i) * T_;
  const float* Gb = G + (size_t)bh * T_;
  float l[8];
  float m = -3e38f;
#pragma unroll
  for (int c = 0; c < 8; ++c) {
    int j = lane + c * 64;
    if (j <= i) { float v = row[j] * 0.125f + Gi - Gb[j]; l[c] = v; m = fmaxf(m, v); }
    else l[c] = -3e38f;
  }
#pragma unroll
  for (int mm = 32; mm >= 1; mm >>= 1) m = fmaxf(m, __shfl_xor(m, mm));
  float ssum = 0.f;
#pragma unroll
  for (int c = 0; c < 8; ++c) {
    int j = lane + c * 64;
    float p = (j <= i) ? expf(l[c] - m) : 0.f;
    l[c] = p; ssum += p;
  }
#pragma unroll
  for (int mm = 32; mm >= 1; mm >>= 1) ssum += __shfl_xor(ssum, mm);
  float inv = 1.f / ssum;
#pragma unroll
  for (int c = 0; c < 8; ++c) row[lane + c * 64] = l[c] * inv;
}

// ======================= o = P @ V (skips zero causal chunks) =======================
__global__ __launch_bounds__(256) void pv_k(const float* __restrict__ P,
                                            const float* __restrict__ vT,
                                            float* __restrict__ o) {
  int it = blockIdx.x, bh = blockIdx.y;
  int b = bh >> 4, h = bh & 15;
  __shared__ float Ps[64][68];
  __shared__ float Vs[64][68];
  const int tid = threadIdx.x;
  const int tm = (tid >> 4) << 2, tn = (tid & 15) << 2;
  float acc[4][4] = {};
  for (int c = 0; c <= it; ++c) {
    __syncthreads();
    for (int l = 0; l < 4; ++l) {
      int f = tid + l * 256;
      int r = f >> 4, c4 = (f & 15) << 2;
      *(float4*)&Ps[r][c4] = *(const float4*)&P[((size_t)bh * T_ + it * 64 + r) * T_ + c * 64 + c4];
      *(float4*)&Vs[r][c4] = *(const float4*)&vT[(((size_t)bh) * T_ + c * 64 + r) * DH + c4];
    }
    __syncthreads();
#pragma unroll
    for (int kk = 0; kk < 64; ++kk) {
      float a0 = Ps[tm + 0][kk], a1 = Ps[tm + 1][kk], a2 = Ps[tm + 2][kk], a3 = Ps[tm + 3][kk];
      float4 bvec = *(const float4*)&Vs[kk][tn];
      acc[0][0] += a0 * bvec.x; acc[0][1] += a0 * bvec.y; acc[0][2] += a0 * bvec.z; acc[0][3] += a0 * bvec.w;
      acc[1][0] += a1 * bvec.x; acc[1][1] += a1 * bvec.y; acc[1][2] += a1 * bvec.z; acc[1][3] += a1 * bvec.w;
      acc[2][0] += a2 * bvec.x; acc[2][1] += a2 * bvec.y; acc[2][2] += a2 * bvec.z; acc[2][3] += a2 * bvec.w;
      acc[3][0] += a3 * bvec.x; acc[3][1] += a3 * bvec.y; acc[3][2] += a3 * bvec.z; acc[3][3] += a3 * bvec.w;
    }
  }
#pragma unroll
  for (int ii = 0; ii < 4; ++ii) {
    int i = it * 64 + tm + ii;
#pragma unroll
    for (int jj = 0; jj < 4; ++jj) {
      o[((size_t)(b * T_ + i)) * D_ + h * 64 + tn + jj] = acc[ii][jj];
    }
  }
}

// ======================= launch =======================
extern "C" void kernel_launch(void* const* d_in, const int* in_sizes, int n_in,
                              void* d_out, int out_size, void* d_ws, size_t ws_size,
                              hipStream_t stream) {
  (void)in_sizes; (void)n_in; (void)out_size; (void)ws_size;
  const float* x     = (const float*)d_in[0];
  const float* Wq    = (const float*)d_in[1];
  const float* Wk    = (const float*)d_in[2];
  const float* Wv    = (const float*)d_in[3];
  const float* Wo    = (const float*)d_in[4];
  const float* wA    = (const float*)d_in[5];
  const float* wB    = (const float*)d_in[6];
  const float* convw = (const float*)d_in[7];
  const float* bw    = (const float*)d_in[8];
  const float* gw    = (const float*)d_in[9];
  const float* gb    = (const float*)d_in[10];
  const float* qnw   = (const float*)d_in[11];
  const float* knw   = (const float*)d_in[12];

  float* ws = (float*)d_ws;
  float* q    = ws;                                   // [BT,D]
  float* k    = q    + (size_t)BT_ * D_;              // [BT,D]
  float* vTb  = k    + (size_t)BT_ * D_;              // [BH,T,dh]
  float* wlow = vTb  + (size_t)BT_ * D_;              // [BT,R]
  float* beta = wlow + (size_t)BT_ * R_;              // [BH,T]
  float* G    = beta + (size_t)BH_ * T_;              // [BH,T]
  float* qTb  = G    + (size_t)BH_ * T_;              // [BH,T,dh]
  float* kTb  = qTb  + (size_t)BT_ * D_;              // [BH,T,dh]
  float* wTb  = kTb  + (size_t)BT_ * D_;              // [BH,T,dh]
  float* Ab   = wTb  + (size_t)BT_ * D_;              // [BH,T,T]
  float* S    = Ab   + (size_t)BH_ * T_ * T_;         // [BH,T,T]
  float* ob   = S    + (size_t)BH_ * T_ * T_;         // [BT,D]

  dim3 g16(16, 16);
  gemm64<0><<<g16, 256, 0, stream>>>(x, Wq, q,   BT_, D_, D_);
  gemm64<0><<<g16, 256, 0, stream>>>(x, Wk, k,   BT_, D_, D_);
  gemm64<1><<<g16, 256, 0, stream>>>(x, Wv, vTb, BT_, D_, D_);
  proj_small<<<BT_, 64, 0, stream>>>(x, wA, bw, gw, gb, wlow, beta, G);
  cumsum_k<<<BH_, 512, 0, stream>>>(G);
  wdir_k<<<BT_, 1024, 0, stream>>>(wlow, wB, convw, wTb);
  rmsT_k<<<BT_, 1024, 0, stream>>>(q, k, qnw, knw, qTb, kTb);
  solve_k<<<dim3(8, BH_), 512, 0, stream>>>(wTb, kTb, beta, Ab);
  s_kernel<<<dim3(8, 8, BH_), 256, 0, stream>>>(qTb, kTb, wTb, Ab, S);
  softmax_k<<<dim3(T_, BH_), 64, 0, stream>>>(S, G);
  pv_k<<<dim3(8, BH_), 256, 0, stream>>>(S, vTb, ob);
  gemm64<0><<<g16, 256, 0, stream>>>(ob, Wo, (float*)d_out, BT_, D_, D_);
}

// Round 2
// 686.267 us; speedup vs baseline: 2.7285x; 2.7285x over previous
//
#include <hip/hip_runtime.h>
#include <hip/hip_bf16.h>
#include <math.h>

#define B_ 2
#define T_ 512
#define D_ 1024
#define H_ 16
#define R_ 32
#define DH 64
#define BT_ (B_*T_)
#define BH_ (B_*H_)

typedef __attribute__((ext_vector_type(8))) short bf16x8;
typedef __attribute__((ext_vector_type(4))) float f32x4;

#define MFMA_BF16(a, b, c) __builtin_amdgcn_mfma_f32_16x16x32_bf16(a, b, c, 0, 0, 0)

// ======================= generic 64x64 fp32 GEMM =======================
// MODE 0: C[M,N] row-major.  MODE 1: scatter output to [B,H,T,dh] (v-transpose).
template<int MODE>
__global__ __launch_bounds__(256) void gemm64(const float* __restrict__ A,
                                              const float* __restrict__ Bm,
                                              float* __restrict__ C,
                                              int M, int N, int K) {
  __shared__ float As[16][64];   // [k][m]
  __shared__ float Bs[16][64];   // [k][n]
  const int bm = blockIdx.y * 64, bn = blockIdx.x * 64;
  const int tid = threadIdx.x;
  const int tm = (tid >> 4) << 2, tn = (tid & 15) << 2;
  const int ar = tid >> 2, ac = (tid & 3) << 2;
  const int br = tid >> 4, bc = (tid & 15) << 2;
  float acc[4][4] = {};
  const float* Ap = A + (size_t)(bm + ar) * K + ac;
  const float* Bp = Bm + (size_t)br * N + bn + bc;
  for (int k0 = 0; k0 < K; k0 += 16) {
    float4 av = *(const float4*)(Ap + k0);
    float4 bv = *(const float4*)(Bp + (size_t)k0 * N);
    __syncthreads();
    As[ac + 0][ar] = av.x; As[ac + 1][ar] = av.y; As[ac + 2][ar] = av.z; As[ac + 3][ar] = av.w;
    *(float4*)&Bs[br][bc] = bv;
    __syncthreads();
#pragma unroll
    for (int kk = 0; kk < 16; ++kk) {
      float4 a = *(const float4*)&As[kk][tm];
      float4 b = *(const float4*)&Bs[kk][tn];
      acc[0][0] += a.x * b.x; acc[0][1] += a.x * b.y; acc[0][2] += a.x * b.z; acc[0][3] += a.x * b.w;
      acc[1][0] += a.y * b.x; acc[1][1] += a.y * b.y; acc[1][2] += a.y * b.z; acc[1][3] += a.y * b.w;
      acc[2][0] += a.z * b.x; acc[2][1] += a.z * b.y; acc[2][2] += a.z * b.z; acc[2][3] += a.z * b.w;
      acc[3][0] += a.w * b.x; acc[3][1] += a.w * b.y; acc[3][2] += a.w * b.z; acc[3][3] += a.w * b.w;
    }
  }
  if (MODE == 0) {
#pragma unroll
    for (int ii = 0; ii < 4; ++ii) {
      float4 r; r.x = acc[ii][0]; r.y = acc[ii][1]; r.z = acc[ii][2]; r.w = acc[ii][3];
      *(float4*)&C[(size_t)(bm + tm + ii) * N + bn + tn] = r;
    }
  } else {
#pragma unroll
    for (int ii = 0; ii < 4; ++ii) {
      int m = bm + tm + ii; int b = m / T_, t = m - b * T_;
#pragma unroll
      for (int jj = 0; jj < 4; ++jj) {
        int n = bn + tn + jj; int h = n >> 6, dd = n & 63;
        C[(((size_t)(b * H_ + h)) * T_ + t) * DH + dd] = acc[ii][jj];
      }
    }
  }
}

// ======================= small projections: wlow, beta, g =======================
__global__ __launch_bounds__(64) void proj_small(const float* __restrict__ x,
                                                 const float* __restrict__ wA,
                                                 const float* __restrict__ bw,
                                                 const float* __restrict__ gw,
                                                 const float* __restrict__ gb,
                                                 float* __restrict__ wlow,
                                                 float* __restrict__ beta,
                                                 float* __restrict__ gout) {
  int bt = blockIdx.x, b = bt / T_, t = bt - b * T_;
  __shared__ float xs[D_];
  int tid = threadIdx.x;
  for (int i = tid * 4; i < D_; i += 256) {
    *(float4*)&xs[i] = *(const float4*)&x[(size_t)bt * D_ + i];
  }
  __syncthreads();
  if (tid < R_) {
    float a = 0.f;
    for (int i = 0; i < D_; ++i) a += xs[i] * wA[(size_t)i * R_ + tid];
    wlow[(size_t)bt * R_ + tid] = a;
  } else if (tid < R_ + H_) {
    int h = tid - R_;
    float a = 0.f;
    for (int i = 0; i < D_; ++i) a += xs[i] * bw[(size_t)i * H_ + h];
    beta[((size_t)(b * H_ + h)) * T_ + t] = 2.f / (1.f + expf(-a));
  } else {
    int h = tid - R_ - H_;
    float a = gb[h];
    for (int i = 0; i < D_; ++i) a += xs[i] * gw[(size_t)i * H_ + h];
    float mn = fminf(a, 0.f);                       // logsigmoid(a)
    gout[((size_t)(b * H_ + h)) * T_ + t] = mn - log1pf(expf(-fabsf(a)));
  }
}

// ======================= inclusive cumsum over T per (b,h) =======================
__global__ __launch_bounds__(512) void cumsum_k(float* __restrict__ G) {
  __shared__ float s[T_];
  int bh = blockIdx.x, t = threadIdx.x;
  s[t] = G[(size_t)bh * T_ + t];
  __syncthreads();
  for (int off = 1; off < T_; off <<= 1) {
    float v = (t >= off) ? s[t - off] : 0.f;
    __syncthreads();
    s[t] += v;
    __syncthreads();
  }
  G[(size_t)bh * T_ + t] = s[t];
}

// ======================= w: low-rank expand + conv3 + silu + unit-normalize ===========
__global__ __launch_bounds__(1024) void wdir_k(const float* __restrict__ wlow,
                                               const float* __restrict__ wB,
                                               const float* __restrict__ convw,
                                               float* __restrict__ wT,
                                               __hip_bfloat16* __restrict__ wb16) {
  int bt = blockIdx.x, b = bt / T_, t = bt - b * T_;
  __shared__ float wl[3][R_];
  int tid = threadIdx.x;
  if (tid < 3 * R_) {
    int row = tid / R_, r = tid - row * R_;
    int ts = t - row;
    wl[row][r] = (ts >= 0) ? wlow[(size_t)(b * T_ + ts) * R_ + r] : 0.f;
  }
  __syncthreads();
  float f0 = 0.f, f1 = 0.f, f2 = 0.f;
  for (int r = 0; r < R_; ++r) {
    float wb = wB[(size_t)r * D_ + tid];
    f0 += wl[0][r] * wb; f1 += wl[1][r] * wb; f2 += wl[2][r] * wb;
  }
  float y = f2 * convw[tid * 3 + 0] + f1 * convw[tid * 3 + 1] + f0 * convw[tid * 3 + 2];
  float s = y / (1.f + expf(-y));                       // silu
  float ss = s * s;
#pragma unroll
  for (int m = 32; m >= 1; m >>= 1) ss += __shfl_xor(ss, m);
  float outv = s * rsqrtf(ss + 1e-12f);
  int h = tid >> 6, dd = tid & 63;
  size_t o = (((size_t)(b * H_ + h)) * T_ + t) * DH + dd;
  wT[o] = outv;
  wb16[o] = __float2bfloat16(outv);
}

// ======================= rmsnorm q,k: kT fp32 (for solve) + q,k bf16 =======================
__global__ __launch_bounds__(1024) void rmsT_k(const float* __restrict__ q,
                                               const float* __restrict__ k,
                                               const float* __restrict__ qnw,
                                               const float* __restrict__ knw,
                                               float* __restrict__ kT,
                                               __hip_bfloat16* __restrict__ qb16,
                                               __hip_bfloat16* __restrict__ kb16) {
  int bt = blockIdx.x, b = bt / T_, t = bt - b * T_;
  int tid = threadIdx.x, h = tid >> 6, dd = tid & 63;
  float qv = q[(size_t)bt * D_ + tid];
  float kv = k[(size_t)bt * D_ + tid];
  float sq = qv * qv, sk = kv * kv;
#pragma unroll
  for (int m = 32; m >= 1; m >>= 1) { sq += __shfl_xor(sq, m); sk += __shfl_xor(sk, m); }
  float qs = qv * rsqrtf(sq * (1.f / DH) + 1e-5f) * qnw[dd];
  float ks = kv * rsqrtf(sk * (1.f / DH) + 1e-5f) * knw[dd];
  size_t o = (((size_t)(b * H_ + h)) * T_ + t) * DH + dd;
  kT[o] = ks;
  qb16[o] = __float2bfloat16(qs);
  kb16[o] = __float2bfloat16(ks);
}

// ======================= UT/WY blocked triangular solve =======================
// Emits AbT bf16: AbT[bh][j][t] = beta_t * A[t][j]  (transposed for MFMA B-operand).
__global__ __launch_bounds__(512) void solve_k(const float* __restrict__ wT,
                                               const float* __restrict__ kT,
                                               const float* __restrict__ beta,
                                               __hip_bfloat16* __restrict__ abT) {
  int ch = blockIdx.x, bh = blockIdx.y;
  __shared__ float KshT[DH][65];   // [dd][j]
  __shared__ float MshT[DH][65];   // [dd][j]
  __shared__ float Wsh[DH][68];    // [r][dd]
  __shared__ float WshT[DH][65];   // [dd][r]
  __shared__ float Ash[DH][65];    // [r][j]
  __shared__ float Csh[DH][65];    // [r][s]
  __shared__ float bI[DH];
  const int tid = threadIdx.x, tx = tid & 63, ty = tid >> 6;   // ty in 0..7

  for (int it = 0; it < 2; ++it) {
    int f = tid + it * 512;
    int j = f >> 4, c4 = (f & 15) << 2;
    float4 v = *(const float4*)&kT[(((size_t)bh) * T_ + ch * 64 + j) * DH + c4];
    KshT[c4 + 0][j] = v.x; KshT[c4 + 1][j] = v.y; KshT[c4 + 2][j] = v.z; KshT[c4 + 3][j] = v.w;
  }
  for (int i = tid; i < DH * 65; i += 512) ((float*)MshT)[i] = 0.f;

  const int jg = ch * 64 + tx;
  for (int I = 0; I < 8; ++I) {
    const int t0 = I * 64;
    __syncthreads();
    for (int it = 0; it < 2; ++it) {
      int f = tid + it * 512;
      int r = f >> 4, c4 = (f & 15) << 2;
      float4 v = *(const float4*)&wT[(((size_t)bh) * T_ + t0 + r) * DH + c4];
      *(float4*)&Wsh[r][c4] = v;
      WshT[c4 + 0][r] = v.x; WshT[c4 + 1][r] = v.y; WshT[c4 + 2][r] = v.z; WshT[c4 + 3][r] = v.w;
    }
    if (tid < 64) bI[tid] = beta[(size_t)bh * T_ + t0 + tid];
    __syncthreads();

    float km[DH];
#pragma unroll
    for (int dd = 0; dd < DH; ++dd) km[dd] = KshT[dd][tx] - MshT[dd][tx];

#pragma unroll
    for (int rr = 0; rr < 8; ++rr) {
      int r = ty * 8 + rr;
      float a = 0.f;
#pragma unroll
      for (int dd = 0; dd < DH; ++dd) a += Wsh[r][dd] * km[dd];
      Ash[r][tx] = (jg < t0 + r) ? a : 0.f;
    }
#pragma unroll
    for (int rr = 0; rr < 8; ++rr) {
      int r = ty * 8 + rr;
      float a = 0.f;
#pragma unroll
      for (int dd = 0; dd < DH; ++dd) a += Wsh[r][dd] * WshT[dd][tx];
      Csh[r][tx] = (tx < r) ? a * bI[tx] : 0.f;
    }
    __syncthreads();

    for (int r = 0; r < 63; ++r) {
      float arj = Ash[r][tx];
      for (int r2 = r + 1 + ty; r2 < 64; r2 += 8) Ash[r2][tx] -= Csh[r2][r] * arj;
      __syncthreads();
    }

#pragma unroll
    for (int rr = 0; rr < 8; ++rr) { int r = ty * 8 + rr; Ash[r][tx] *= bI[r]; }
    __syncthreads();

#pragma unroll
    for (int dq = 0; dq < 8; ++dq) {
      int dd = ty * 8 + dq;
      float a = MshT[dd][tx];
#pragma unroll
      for (int s = 0; s < 64; ++s) a += WshT[dd][s] * Ash[s][tx];
      MshT[dd][tx] = a;
    }
    // transposed bf16 write: AbT[j][t] = Ash[t][j]; coalesced along t=tx.
#pragma unroll
    for (int rr = 0; rr < 8; ++rr) {
      int j = ty * 8 + rr;
      abT[((size_t)bh * T_ + ch * 64 + j) * T_ + t0 + tx] = __float2bfloat16(Ash[tx][j]);
    }
  }
}

// ======================= S via MFMA: S = Q K^T - tril(Q W^T) @ (beta A) =======================
// grid (tileIdx in lower triangle [36], bh). 64x64 tile, 4 waves (one 16-row slab each).
__device__ __forceinline__ bf16x8 ldfrag(const __hip_bfloat16 s[][72], int b16, int kb, int fr, int kq) {
  return *(const bf16x8*)&s[b16 * 16 + fr][kb * 32 + kq * 8];
}
__device__ __forceinline__ void stage64(const __hip_bfloat16* __restrict__ g, int ldg,
                                        __hip_bfloat16 s[][72], int tid) {
#pragma unroll
  for (int l = 0; l < 2; ++l) {
    int f = tid + l * 256;
    int r = f >> 3, c = (f & 7) << 3;
    *(int4*)&s[r][c] = *(const int4*)&g[(size_t)r * ldg + c];
  }
}

__global__ __launch_bounds__(256) void s_mfma(const __hip_bfloat16* __restrict__ qb,
                                              const __hip_bfloat16* __restrict__ kb,
                                              const __hip_bfloat16* __restrict__ wb,
                                              const __hip_bfloat16* __restrict__ abT,
                                              float* __restrict__ S) {
  __shared__ __hip_bfloat16 Qs[64][72];   // Q tile  [i][d]
  __shared__ __hip_bfloat16 Bs[64][72];   // K or W tile [t][d]
  __shared__ __hip_bfloat16 Cs[64][72];   // AbT tile [j][t]
  __shared__ __hip_bfloat16 Ms[64][72];   // masked -qw [i][t]
  int ti = blockIdx.x;
  int it = 0, accum = 0;
  while (accum + it + 1 <= ti) { accum += it + 1; ++it; }
  const int jt = ti - accum;
  const int bh = blockIdx.y;
  const int tid = threadIdx.x, w = tid >> 6, lane = tid & 63;
  const int fr = lane & 15, kq = lane >> 4;
  const size_t hb = (size_t)bh * T_;

  stage64(qb + (hb + it * 64) * DH, DH, Qs, tid);
  stage64(kb + (hb + jt * 64) * DH, DH, Bs, tid);
  __syncthreads();

  const bf16x8 a0 = ldfrag(Qs, w, 0, fr, kq);
  const bf16x8 a1 = ldfrag(Qs, w, 1, fr, kq);

  f32x4 acc[4];
  const f32x4 zero = {0.f, 0.f, 0.f, 0.f};
#pragma unroll
  for (int nb = 0; nb < 4; ++nb) {
    acc[nb] = MFMA_BF16(a0, ldfrag(Bs, nb, 0, fr, kq), zero);
    acc[nb] = MFMA_BF16(a1, ldfrag(Bs, nb, 1, fr, kq), acc[nb]);
  }

  for (int c = jt; c <= it; ++c) {
    __syncthreads();   // previous consumers of Bs/Cs/Ms done
    stage64(wb + (hb + c * 64) * DH, DH, Bs, tid);
    stage64(abT + (hb + jt * 64) * T_ + c * 64, T_, Cs, tid);
    __syncthreads();
    // qw = Q . W^T over d
    f32x4 qw[4];
#pragma unroll
    for (int nb = 0; nb < 4; ++nb) {
      qw[nb] = MFMA_BF16(a0, ldfrag(Bs, nb, 0, fr, kq), zero);
      qw[nb] = MFMA_BF16(a1, ldfrag(Bs, nb, 1, fr, kq), qw[nb]);
    }
    // mask (t<=i), negate, bf16 -> Ms[i][t]
    const int row0 = w * 16 + kq * 4;
    const bool diag = (c == it);
#pragma unroll
    for (int nb = 0; nb < 4; ++nb) {
      int col = nb * 16 + fr;
#pragma unroll
      for (int reg = 0; reg < 4; ++reg) {
        float v = -qw[nb][reg];
        if (diag && col > row0 + reg) v = 0.f;
        Ms[row0 + reg][col] = __float2bfloat16(v);
      }
    }
    __syncthreads();
    // acc += (-qw)[i][t] . Ab[t][j]   (B^T = AbT[j][t])
    const bf16x8 m0 = ldfrag(Ms, w, 0, fr, kq);
    const bf16x8 m1 = ldfrag(Ms, w, 1, fr, kq);
#pragma unroll
    for (int nb = 0; nb < 4; ++nb) {
      acc[nb] = MFMA_BF16(m0, ldfrag(Cs, nb, 0, fr, kq), acc[nb]);
      acc[nb] = MFMA_BF16(m1, ldfrag(Cs, nb, 1, fr, kq), acc[nb]);
    }
  }
  // write S tile: C/D layout col=lane&15, row=kq*4+reg
#pragma unroll
  for (int nb = 0; nb < 4; ++nb) {
    int j = jt * 64 + nb * 16 + fr;
#pragma unroll
    for (int reg = 0; reg < 4; ++reg) {
      S[(hb + it * 64 + w * 16 + kq * 4 + reg) * T_ + j] = acc[nb][reg];
    }
  }
}

// ======================= softmax with gate-cumsum bias, causal =======================
__global__ __launch_bounds__(64) void softmax_k(float* __restrict__ S, const float* __restrict__ G) {
  int i = blockIdx.x, bh = blockIdx.y;
  int lane = threadIdx.x;
  const float Gi = G[(size_t)bh * T_ + i];
  float* row = S + ((size_t)bh * T_ + i) * T_;
  const float* Gb = G + (size_t)bh * T_;
  float l[8];
  float m = -3e38f;
#pragma unroll
  for (int c = 0; c < 8; ++c) {
    int j = lane + c * 64;
    if (j <= i) { float v = row[j] * 0.125f + Gi - Gb[j]; l[c] = v; m = fmaxf(m, v); }
    else l[c] = -3e38f;
  }
#pragma unroll
  for (int mm = 32; mm >= 1; mm >>= 1) m = fmaxf(m, __shfl_xor(m, mm));
  float ssum = 0.f;
#pragma unroll
  for (int c = 0; c < 8; ++c) {
    int j = lane + c * 64;
    float p = (j <= i) ? expf(l[c] - m) : 0.f;
    l[c] = p; ssum += p;
  }
#pragma unroll
  for (int mm = 32; mm >= 1; mm >>= 1) ssum += __shfl_xor(ssum, mm);
  float inv = 1.f / ssum;
#pragma unroll
  for (int c = 0; c < 8; ++c) row[lane + c * 64] = l[c] * inv;
}

// ======================= o = P @ V (skips zero causal chunks) =======================
__global__ __launch_bounds__(256) void pv_k(const float* __restrict__ P,
                                            const float* __restrict__ vT,
                                            float* __restrict__ o) {
  int it = blockIdx.x, bh = blockIdx.y;
  int b = bh >> 4, h = bh & 15;
  __shared__ float Ps[64][68];
  __shared__ float Vs[64][68];
  const int tid = threadIdx.x;
  const int tm = (tid >> 4) << 2, tn = (tid & 15) << 2;
  float acc[4][4] = {};
  for (int c = 0; c <= it; ++c) {
    __syncthreads();
    for (int l = 0; l < 4; ++l) {
      int f = tid + l * 256;
      int r = f >> 4, c4 = (f & 15) << 2;
      *(float4*)&Ps[r][c4] = *(const float4*)&P[((size_t)bh * T_ + it * 64 + r) * T_ + c * 64 + c4];
      *(float4*)&Vs[r][c4] = *(const float4*)&vT[(((size_t)bh) * T_ + c * 64 + r) * DH + c4];
    }
    __syncthreads();
#pragma unroll
    for (int kk = 0; kk < 64; ++kk) {
      float a0 = Ps[tm + 0][kk], a1 = Ps[tm + 1][kk], a2 = Ps[tm + 2][kk], a3 = Ps[tm + 3][kk];
      float4 bvec = *(const float4*)&Vs[kk][tn];
      acc[0][0] += a0 * bvec.x; acc[0][1] += a0 * bvec.y; acc[0][2] += a0 * bvec.z; acc[0][3] += a0 * bvec.w;
      acc[1][0] += a1 * bvec.x; acc[1][1] += a1 * bvec.y; acc[1][2] += a1 * bvec.z; acc[1][3] += a1 * bvec.w;
      acc[2][0] += a2 * bvec.x; acc[2][1] += a2 * bvec.y; acc[2][2] += a2 * bvec.z; acc[2][3] += a2 * bvec.w;
      acc[3][0] += a3 * bvec.x; acc[3][1] += a3 * bvec.y; acc[3][2] += a3 * bvec.z; acc[3][3] += a3 * bvec.w;
    }
  }
#pragma unroll
  for (int ii = 0; ii < 4; ++ii) {
    int i = it * 64 + tm + ii;
#pragma unroll
    for (int jj = 0; jj < 4; ++jj) {
      o[((size_t)(b * T_ + i)) * D_ + h * 64 + tn + jj] = acc[ii][jj];
    }
  }
}

// ======================= launch =======================
extern "C" void kernel_launch(void* const* d_in, const int* in_sizes, int n_in,
                              void* d_out, int out_size, void* d_ws, size_t ws_size,
                              hipStream_t stream) {
  (void)in_sizes; (void)n_in; (void)out_size; (void)ws_size;
  const float* x     = (const float*)d_in[0];
  const float* Wq    = (const float*)d_in[1];
  const float* Wk    = (const float*)d_in[2];
  const float* Wv    = (const float*)d_in[3];
  const float* Wo    = (const float*)d_in[4];
  const float* wA    = (const float*)d_in[5];
  const float* wB    = (const float*)d_in[6];
  const float* convw = (const float*)d_in[7];
  const float* bw    = (const float*)d_in[8];
  const float* gw    = (const float*)d_in[9];
  const float* gb    = (const float*)d_in[10];
  const float* qnw   = (const float*)d_in[11];
  const float* knw   = (const float*)d_in[12];

  const size_t N1 = (size_t)BT_ * D_;          // 1M elems
  float* ws = (float*)d_ws;
  float* q    = ws;                // [BT,D]
  float* k    = q  + N1;           // [BT,D]
  float* vTb  = k  + N1;           // [BH,T,dh] fp32 (for pv)
  float* kTb  = vTb + N1;          // [BH,T,dh] fp32 (for solve)
  float* wTb  = kTb + N1;          // [BH,T,dh] fp32 (for solve)
  float* ob   = wTb + N1;          // [BT,D]
  float* S    = ob  + N1;          // [BH,T,T] fp32
  float* wlow = S   + (size_t)BH_ * T_ * T_;   // [BT,R]
  float* beta = wlow + (size_t)BT_ * R_;       // [BH,T]
  float* G    = beta + (size_t)BH_ * T_;       // [BH,T]
  __hip_bfloat16* qb16 = (__hip_bfloat16*)(G + (size_t)BH_ * T_);
  __hip_bfloat16* kb16 = qb16 + N1;
  __hip_bfloat16* wb16 = kb16 + N1;
  __hip_bfloat16* abT  = wb16 + N1;            // [BH,T,T] bf16 (transposed: [j][t])

  dim3 g16(16, 16);
  gemm64<0><<<g16, 256, 0, stream>>>(x, Wq, q,   BT_, D_, D_);
  gemm64<0><<<g16, 256, 0, stream>>>(x, Wk, k,   BT_, D_, D_);
  gemm64<1><<<g16, 256, 0, stream>>>(x, Wv, vTb, BT_, D_, D_);
  proj_small<<<BT_, 64, 0, stream>>>(x, wA, bw, gw, gb, wlow, beta, G);
  cumsum_k<<<BH_, 512, 0, stream>>>(G);
  wdir_k<<<BT_, 1024, 0, stream>>>(wlow, wB, convw, wTb, wb16);
  rmsT_k<<<BT_, 1024, 0, stream>>>(q, k, qnw, knw, kTb, qb16, kb16);
  solve_k<<<dim3(8, BH_), 512, 0, stream>>>(wTb, kTb, beta, abT);
  s_mfma<<<dim3(36, BH_), 256, 0, stream>>>(qb16, kb16, wb16, abT, S);
  softmax_k<<<dim3(T_, BH_), 64, 0, stream>>>(S, G);
  pv_k<<<dim3(8, BH_), 256, 0, stream>>>(S, vTb, ob);
  gemm64<0><<<g16, 256, 0, stream>>>(ob, Wo, (float*)d_out, BT_, D_, D_);
}

// Round 3
// 287.307 us; speedup vs baseline: 6.5174x; 2.3886x over previous
//
#include <hip/hip_runtime.h>
#include <hip/hip_bf16.h>
#include <math.h>

#define B_ 2
#define T_ 512
#define D_ 1024
#define H_ 16
#define R_ 32
#define DH 64
#define BT_ (B_*T_)
#define BH_ (B_*H_)

typedef __attribute__((ext_vector_type(8))) short bf16x8;
typedef __attribute__((ext_vector_type(4))) short s16x4;
typedef __attribute__((ext_vector_type(4))) float f32x4;

#define MFMA_BF16(a, b, c) __builtin_amdgcn_mfma_f32_16x16x32_bf16(a, b, c, 0, 0, 0)

static __device__ __forceinline__ short bf16s(float v) {
  __hip_bfloat16 b = __float2bfloat16(v);
  return *reinterpret_cast<short*>(&b);
}

// ---- shared MFMA helpers (layout verified in R2's s_mfma) ----
__device__ __forceinline__ bf16x8 ldfrag(const __hip_bfloat16 s[][72], int b16, int kb, int fr, int kq) {
  return *(const bf16x8*)&s[b16 * 16 + fr][kb * 32 + kq * 8];
}
__device__ __forceinline__ void stage64(const __hip_bfloat16* __restrict__ g, int ldg,
                                        __hip_bfloat16 s[][72], int tid) {
#pragma unroll
  for (int l = 0; l < 2; ++l) {
    int f = tid + l * 256;
    int r = f >> 3, c = (f & 7) << 3;
    *(int4*)&s[r][c] = *(const int4*)&g[(size_t)r * ldg + c];
  }
}

// ======================= split fp32 -> bf16 hi/lo =======================
__global__ __launch_bounds__(256) void split_f32(const float* __restrict__ in,
                                                 __hip_bfloat16* __restrict__ hi,
                                                 __hip_bfloat16* __restrict__ lo) {
  int i4 = blockIdx.x * 256 + threadIdx.x;
  float4 v = ((const float4*)in)[i4];
  s16x4 ph, pl;
  float c[4] = {v.x, v.y, v.z, v.w};
#pragma unroll
  for (int u = 0; u < 4; ++u) {
    __hip_bfloat16 h = __float2bfloat16(c[u]);
    ph[u] = *reinterpret_cast<short*>(&h);
    pl[u] = bf16s(c[u] - __bfloat162float(h));
  }
  ((s16x4*)hi)[i4] = ph;
  ((s16x4*)lo)[i4] = pl;
}

// ======================= transpose + split weights: W[K][N] -> WT hi/lo [N][K] ============
__global__ __launch_bounds__(256) void splitT_k(const float* __restrict__ Wm,
                                                __hip_bfloat16* __restrict__ thi,
                                                __hip_bfloat16* __restrict__ tlo) {
  __shared__ float tile[64][65];
  const int bn = blockIdx.x * 64, bk = blockIdx.y * 64;
  const int tid = threadIdx.x;
#pragma unroll
  for (int l = 0; l < 4; ++l) {
    int f = tid + l * 256; int r = f >> 4, c = (f & 15) << 2;
    *(float4*)&tile[r][c] = *(const float4*)&Wm[(size_t)(bk + r) * D_ + bn + c];
  }
  __syncthreads();
#pragma unroll
  for (int l = 0; l < 4; ++l) {
    int f = tid + l * 256; int n = f >> 4, k0 = (f & 15) << 2;
    s16x4 ph, pl;
#pragma unroll
    for (int u = 0; u < 4; ++u) {
      float v = tile[k0 + u][n];
      __hip_bfloat16 h = __float2bfloat16(v);
      ph[u] = *reinterpret_cast<short*>(&h);
      pl[u] = bf16s(v - __bfloat162float(h));
    }
    *(s16x4*)&thi[(size_t)(bn + n) * D_ + bk + k0] = ph;
    *(s16x4*)&tlo[(size_t)(bn + n) * D_ + bk + k0] = pl;
  }
}

// ======================= fp32-class GEMM via 3x bf16 MFMA =======================
// C = (ahi+alo) @ (bhi+blo)^T   (b* given as [N][K] transposed tiles)
// MODE 0: C[M,N] row-major fp32.  MODE 1: scatter to vT [B,H,T,dh] fp32.
template<int MODE>
__global__ __launch_bounds__(256) void gemm_split(const __hip_bfloat16* __restrict__ ah,
                                                  const __hip_bfloat16* __restrict__ al,
                                                  const __hip_bfloat16* __restrict__ bh,
                                                  const __hip_bfloat16* __restrict__ bl,
                                                  float* __restrict__ C) {
  __shared__ __hip_bfloat16 Ah[64][72], Al[64][72], Bh[64][72], Bl[64][72];
  const int bm = blockIdx.y * 64, bn = blockIdx.x * 64;
  const int tid = threadIdx.x, w = tid >> 6, lane = tid & 63;
  const int fr = lane & 15, kq = lane >> 4;
  const f32x4 zf = {0.f, 0.f, 0.f, 0.f};
  f32x4 acc[4] = {zf, zf, zf, zf};
  for (int k0 = 0; k0 < D_; k0 += 64) {
    __syncthreads();
    stage64(ah + (size_t)bm * D_ + k0, D_, Ah, tid);
    stage64(al + (size_t)bm * D_ + k0, D_, Al, tid);
    stage64(bh + (size_t)bn * D_ + k0, D_, Bh, tid);
    stage64(bl + (size_t)bn * D_ + k0, D_, Bl, tid);
    __syncthreads();
    bf16x8 ah0 = ldfrag(Ah, w, 0, fr, kq), ah1 = ldfrag(Ah, w, 1, fr, kq);
    bf16x8 al0 = ldfrag(Al, w, 0, fr, kq), al1 = ldfrag(Al, w, 1, fr, kq);
#pragma unroll
    for (int nb = 0; nb < 4; ++nb) {
      bf16x8 b0 = ldfrag(Bh, nb, 0, fr, kq), b1 = ldfrag(Bh, nb, 1, fr, kq);
      bf16x8 c0 = ldfrag(Bl, nb, 0, fr, kq), c1 = ldfrag(Bl, nb, 1, fr, kq);
      acc[nb] = MFMA_BF16(ah0, b0, acc[nb]); acc[nb] = MFMA_BF16(ah1, b1, acc[nb]);
      acc[nb] = MFMA_BF16(ah0, c0, acc[nb]); acc[nb] = MFMA_BF16(ah1, c1, acc[nb]);
      acc[nb] = MFMA_BF16(al0, b0, acc[nb]); acc[nb] = MFMA_BF16(al1, b1, acc[nb]);
    }
  }
#pragma unroll
  for (int nb = 0; nb < 4; ++nb) {
    int n = bn + nb * 16 + fr;
#pragma unroll
    for (int reg = 0; reg < 4; ++reg) {
      int m = bm + w * 16 + kq * 4 + reg;
      if (MODE == 0) {
        C[(size_t)m * D_ + n] = acc[nb][reg];
      } else {
        int b = m >> 9, t = m & 511, h = n >> 6, dd = n & 63;
        C[(((size_t)(b * H_ + h)) * T_ + t) * DH + dd] = acc[nb][reg];
      }
    }
  }
}

// ======================= small projections: wlow, beta, g =======================
__global__ __launch_bounds__(64) void proj_small(const float* __restrict__ x,
                                                 const float* __restrict__ wA,
                                                 const float* __restrict__ bw,
                                                 const float* __restrict__ gw,
                                                 const float* __restrict__ gb,
                                                 float* __restrict__ wlow,
                                                 float* __restrict__ beta,
                                                 float* __restrict__ gout) {
  int bt = blockIdx.x, b = bt / T_, t = bt - b * T_;
  __shared__ float xs[D_];
  int tid = threadIdx.x;
  for (int i = tid * 4; i < D_; i += 256) {
    *(float4*)&xs[i] = *(const float4*)&x[(size_t)bt * D_ + i];
  }
  __syncthreads();
  if (tid < R_) {
    float a = 0.f;
    for (int i = 0; i < D_; ++i) a += xs[i] * wA[(size_t)i * R_ + tid];
    wlow[(size_t)bt * R_ + tid] = a;
  } else if (tid < R_ + H_) {
    int h = tid - R_;
    float a = 0.f;
    for (int i = 0; i < D_; ++i) a += xs[i] * bw[(size_t)i * H_ + h];
    beta[((size_t)(b * H_ + h)) * T_ + t] = 2.f / (1.f + expf(-a));
  } else {
    int h = tid - R_ - H_;
    float a = gb[h];
    for (int i = 0; i < D_; ++i) a += xs[i] * gw[(size_t)i * H_ + h];
    float mn = fminf(a, 0.f);                       // logsigmoid(a)
    gout[((size_t)(b * H_ + h)) * T_ + t] = mn - log1pf(expf(-fabsf(a)));
  }
}

// ======================= inclusive cumsum over T per (b,h) =======================
__global__ __launch_bounds__(512) void cumsum_k(float* __restrict__ G) {
  __shared__ float s[T_];
  int bh = blockIdx.x, t = threadIdx.x;
  s[t] = G[(size_t)bh * T_ + t];
  __syncthreads();
  for (int off = 1; off < T_; off <<= 1) {
    float v = (t >= off) ? s[t - off] : 0.f;
    __syncthreads();
    s[t] += v;
    __syncthreads();
  }
  G[(size_t)bh * T_ + t] = s[t];
}

// ======================= w: low-rank expand + conv3 + silu + unit-normalize ===========
__global__ __launch_bounds__(1024) void wdir_k(const float* __restrict__ wlow,
                                               const float* __restrict__ wB,
                                               const float* __restrict__ convw,
                                               float* __restrict__ wT,
                                               __hip_bfloat16* __restrict__ wb16) {
  int bt = blockIdx.x, b = bt / T_, t = bt - b * T_;
  __shared__ float wl[3][R_];
  int tid = threadIdx.x;
  if (tid < 3 * R_) {
    int row = tid / R_, r = tid - row * R_;
    int ts = t - row;
    wl[row][r] = (ts >= 0) ? wlow[(size_t)(b * T_ + ts) * R_ + r] : 0.f;
  }
  __syncthreads();
  float f0 = 0.f, f1 = 0.f, f2 = 0.f;
  for (int r = 0; r < R_; ++r) {
    float wb = wB[(size_t)r * D_ + tid];
    f0 += wl[0][r] * wb; f1 += wl[1][r] * wb; f2 += wl[2][r] * wb;
  }
  float y = f2 * convw[tid * 3 + 0] + f1 * convw[tid * 3 + 1] + f0 * convw[tid * 3 + 2];
  float s = y / (1.f + expf(-y));                       // silu
  float ss = s * s;
#pragma unroll
  for (int m = 32; m >= 1; m >>= 1) ss += __shfl_xor(ss, m);
  float outv = s * rsqrtf(ss + 1e-12f);
  int h = tid >> 6, dd = tid & 63;
  size_t o = (((size_t)(b * H_ + h)) * T_ + t) * DH + dd;
  wT[o] = outv;
  wb16[o] = __float2bfloat16(outv);
}

// ======================= rmsnorm q,k -> bf16 [B,H,T,dh] =======================
__global__ __launch_bounds__(1024) void rmsT_k(const float* __restrict__ q,
                                               const float* __restrict__ k,
                                               const float* __restrict__ qnw,
                                               const float* __restrict__ knw,
                                               __hip_bfloat16* __restrict__ qb16,
                                               __hip_bfloat16* __restrict__ kb16) {
  int bt = blockIdx.x, b = bt / T_, t = bt - b * T_;
  int tid = threadIdx.x, h = tid >> 6, dd = tid & 63;
  float qv = q[(size_t)bt * D_ + tid];
  float kv = k[(size_t)bt * D_ + tid];
  float sq = qv * qv, sk = kv * kv;
#pragma unroll
  for (int m = 32; m >= 1; m >>= 1) { sq += __shfl_xor(sq, m); sk += __shfl_xor(sk, m); }
  float qs = qv * rsqrtf(sq * (1.f / DH) + 1e-5f) * qnw[dd];
  float ks = kv * rsqrtf(sk * (1.f / DH) + 1e-5f) * knw[dd];
  size_t o = (((size_t)(b * H_ + h)) * T_ + t) * DH + dd;
  qb16[o] = __float2bfloat16(qs);
  kb16[o] = __float2bfloat16(ks);
}

// ======================= per-block unit-lower-triangular inverse =======================
// L = I + tril(C,-1), C[r][s] = (w_r.w_s) * beta_s.  Linv bf16 [bh][8][64][64].
__global__ __launch_bounds__(256) void linv_k(const float* __restrict__ wT,
                                              const float* __restrict__ beta,
                                              __hip_bfloat16* __restrict__ linv) {
  __shared__ float Wsh[64][68];
  __shared__ float Csh[64][65];
  __shared__ float Li[64][68];
  __shared__ float bI[64];
  const int I = blockIdx.x, bhx = blockIdx.y;
  const int tid = threadIdx.x;
#pragma unroll
  for (int l = 0; l < 4; ++l) {
    int f = tid + l * 256; int r = f >> 4, c = (f & 15) << 2;
    *(float4*)&Wsh[r][c] = *(const float4*)&wT[((size_t)bhx * T_ + I * 64 + r) * DH + c];
  }
  if (tid < 64) bI[tid] = beta[(size_t)bhx * T_ + I * 64 + tid];
#pragma unroll
  for (int l = 0; l < 16; ++l) {
    int e = tid + l * 256; int r = e >> 6, c = e & 63;
    Li[r][c] = (r == c) ? 1.f : 0.f;
  }
  __syncthreads();
  const int tm = (tid >> 4) << 2, tn = (tid & 15) << 2;
  float cc[4][4] = {};
  for (int dd = 0; dd < 64; ++dd) {
    float a0 = Wsh[tm + 0][dd], a1 = Wsh[tm + 1][dd], a2 = Wsh[tm + 2][dd], a3 = Wsh[tm + 3][dd];
    float b0 = Wsh[tn + 0][dd], b1 = Wsh[tn + 1][dd], b2 = Wsh[tn + 2][dd], b3 = Wsh[tn + 3][dd];
    cc[0][0] += a0 * b0; cc[0][1] += a0 * b1; cc[0][2] += a0 * b2; cc[0][3] += a0 * b3;
    cc[1][0] += a1 * b0; cc[1][1] += a1 * b1; cc[1][2] += a1 * b2; cc[1][3] += a1 * b3;
    cc[2][0] += a2 * b0; cc[2][1] += a2 * b1; cc[2][2] += a2 * b2; cc[2][3] += a2 * b3;
    cc[3][0] += a3 * b0; cc[3][1] += a3 * b1; cc[3][2] += a3 * b2; cc[3][3] += a3 * b3;
  }
#pragma unroll
  for (int ii = 0; ii < 4; ++ii)
#pragma unroll
    for (int jj = 0; jj < 4; ++jj)
      Csh[tm + ii][tn + jj] = (tm + ii > tn + jj) ? cc[ii][jj] * bI[tn + jj] : 0.f;
  __syncthreads();
  // forward substitution on identity RHS (row r final after step r-1)
  const int sL = tid & 63, g = tid >> 6;
  for (int r = 0; r < 63; ++r) {
    float lr = Li[r][sL];
    for (int r2 = r + 1 + g; r2 < 64; r2 += 4)
      Li[r2][sL] -= Csh[r2][r] * lr;
    __syncthreads();
  }
#pragma unroll
  for (int l = 0; l < 4; ++l) {
    int f = tid + l * 256; int r = f >> 4, c0 = (f & 15) << 2;
    s16x4 p;
    p.x = bf16s(Li[r][c0 + 0]); p.y = bf16s(Li[r][c0 + 1]);
    p.z = bf16s(Li[r][c0 + 2]); p.w = bf16s(Li[r][c0 + 3]);
    *(s16x4*)&linv[((size_t)(bhx * 8 + I)) * 4096 + r * 64 + c0] = p;
  }
}

// ======================= WY chain: per column-chunk, MFMA recurrence =======================
// For chunk ch (cols j), I = ch..7:  PT[j][t] = sum_d (K[j][d]-M[j][d]) W[t][d]  (mask t>j at I==ch)
//   A[t][j] = sum_s Linv[t][s] PT[j][s];  X[j][t] = beta_t A[t][j] -> abT;  M[j][d] += sum_t X[j][t] W[t][d]
__global__ __launch_bounds__(256) void chain_k(const __hip_bfloat16* __restrict__ kb,
                                               const __hip_bfloat16* __restrict__ wb,
                                               const __hip_bfloat16* __restrict__ linv,
                                               const float* __restrict__ beta,
                                               __hip_bfloat16* __restrict__ abT) {
  __shared__ __hip_bfloat16 Kb[64][72];   // [j][d]
  __shared__ __hip_bfloat16 Ws[64][72];   // [t][d]
  __shared__ __hip_bfloat16 WsT[64][72];  // [d][t]
  __shared__ __hip_bfloat16 Ls[64][72];   // [t][s]
  __shared__ __hip_bfloat16 Mhi[64][72];  // [j][d] = -M hi
  __shared__ __hip_bfloat16 Mlo[64][72];  // [j][d] = -M lo
  __shared__ __hip_bfloat16 Ps[64][72];   // [j][t] PT, then reused as X
  __shared__ float bI[64];
  const int ch = blockIdx.x, bhx = blockIdx.y;
  const int tid = threadIdx.x, w = tid >> 6, lane = tid & 63;
  const int fr = lane & 15, kq = lane >> 4;
  const size_t hb = (size_t)bhx * T_;
  const f32x4 zf = {0.f, 0.f, 0.f, 0.f};

  stage64(kb + (hb + ch * 64) * DH, DH, Kb, tid);
  for (int f = tid; f < 576; f += 256) {
    ((int4*)Mhi)[f] = make_int4(0, 0, 0, 0);
    ((int4*)Mlo)[f] = make_int4(0, 0, 0, 0);
  }
  f32x4 macc[4] = {zf, zf, zf, zf};   // +M, rows j = w*16+kq*4+reg, cols d = nb*16+fr

  for (int I = ch; I < 8; ++I) {
    __syncthreads();                                           // B1: prev iter consumers done
    stage64(wb + (hb + I * 64) * DH, DH, Ws, tid);
    stage64(linv + ((size_t)(bhx * 8 + I)) * 4096, 64, Ls, tid);
    if (tid < 64) bI[tid] = beta[hb + I * 64 + tid];
    const int jr = w * 16 + kq * 4;
    if (I > ch) {
#pragma unroll
      for (int nb = 0; nb < 4; ++nb) {
        int d = nb * 16 + fr;
#pragma unroll
        for (int reg = 0; reg < 4; ++reg) {
          float m = -macc[nb][reg];
          __hip_bfloat16 h = __float2bfloat16(m);
          Mhi[jr + reg][d] = h;
          Mlo[jr + reg][d] = __float2bfloat16(m - __bfloat162float(h));
        }
      }
    }
    __syncthreads();                                           // B2
    // LDS transpose of W (needed as B-operand of the M update)
#pragma unroll
    for (int l = 0; l < 16; ++l) {
      int e = tid + l * 256;
      int t = e >> 6, d = e & 63;
      WsT[d][t] = Ws[t][d];
    }
    // PT = Kb @ Ws^T + (-M)hi @ Ws^T + (-M)lo @ Ws^T
    bf16x8 kb0 = ldfrag(Kb, w, 0, fr, kq), kb1 = ldfrag(Kb, w, 1, fr, kq);
    f32x4 pt[4];
#pragma unroll
    for (int nb = 0; nb < 4; ++nb) {
      bf16x8 b0 = ldfrag(Ws, nb, 0, fr, kq), b1 = ldfrag(Ws, nb, 1, fr, kq);
      pt[nb] = MFMA_BF16(kb0, b0, zf);
      pt[nb] = MFMA_BF16(kb1, b1, pt[nb]);
      if (I > ch) {
        bf16x8 mh0 = ldfrag(Mhi, w, 0, fr, kq), mh1 = ldfrag(Mhi, w, 1, fr, kq);
        bf16x8 ml0 = ldfrag(Mlo, w, 0, fr, kq), ml1 = ldfrag(Mlo, w, 1, fr, kq);
        pt[nb] = MFMA_BF16(mh0, b0, pt[nb]); pt[nb] = MFMA_BF16(mh1, b1, pt[nb]);
        pt[nb] = MFMA_BF16(ml0, b0, pt[nb]); pt[nb] = MFMA_BF16(ml1, b1, pt[nb]);
      }
    }
    // mask (keep t>j at diagonal block) and store PT -> Ps[j][t]
#pragma unroll
    for (int nb = 0; nb < 4; ++nb) {
      int t = nb * 16 + fr;
#pragma unroll
      for (int reg = 0; reg < 4; ++reg) {
        float v = pt[nb][reg];
        if (I == ch && t <= jr + reg) v = 0.f;
        Ps[jr + reg][t] = __float2bfloat16(v);
      }
    }
    __syncthreads();                                           // B3
    // A = Ls @ Ps^T  (rows t, cols j)
    bf16x8 la0 = ldfrag(Ls, w, 0, fr, kq), la1 = ldfrag(Ls, w, 1, fr, kq);
    f32x4 av[4];
#pragma unroll
    for (int nb = 0; nb < 4; ++nb) {
      bf16x8 p0 = ldfrag(Ps, nb, 0, fr, kq), p1 = ldfrag(Ps, nb, 1, fr, kq);
      av[nb] = MFMA_BF16(la0, p0, zf);
      av[nb] = MFMA_BF16(la1, p1, av[nb]);
    }
    __syncthreads();                                           // B4: all reads of Ps done
    // X = (beta*A)^T -> Ps[j][t] (packed 4 bf16 along t)
    const int tr = w * 16 + kq * 4;
#pragma unroll
    for (int nb = 0; nb < 4; ++nb) {
      s16x4 p;
      p.x = bf16s(bI[tr + 0] * av[nb][0]);
      p.y = bf16s(bI[tr + 1] * av[nb][1]);
      p.z = bf16s(bI[tr + 2] * av[nb][2]);
      p.w = bf16s(bI[tr + 3] * av[nb][3]);
      *(s16x4*)&Ps[nb * 16 + fr][tr] = p;
    }
    __syncthreads();                                           // B5
    // abT write (coalesced rows) + M update
#pragma unroll
    for (int l = 0; l < 2; ++l) {
      int f = tid + l * 256;
      int r = f >> 3, c = (f & 7) << 3;
      *(int4*)&abT[(hb + ch * 64 + r) * T_ + I * 64 + c] = *(const int4*)&Ps[r][c];
    }
    bf16x8 xa0 = ldfrag(Ps, w, 0, fr, kq), xa1 = ldfrag(Ps, w, 1, fr, kq);
#pragma unroll
    for (int nb = 0; nb < 4; ++nb) {
      bf16x8 wt0 = ldfrag(WsT, nb, 0, fr, kq), wt1 = ldfrag(WsT, nb, 1, fr, kq);
      macc[nb] = MFMA_BF16(xa0, wt0, macc[nb]);
      macc[nb] = MFMA_BF16(xa1, wt1, macc[nb]);
    }
  }
}

// ======================= S via MFMA: S = Q K^T - tril(Q W^T) @ (beta A) =======================
__global__ __launch_bounds__(256) void s_mfma(const __hip_bfloat16* __restrict__ qb,
                                              const __hip_bfloat16* __restrict__ kb,
                                              const __hip_bfloat16* __restrict__ wb,
                                              const __hip_bfloat16* __restrict__ abT,
                                              float* __restrict__ S) {
  __shared__ __hip_bfloat16 Qs[64][72];   // Q tile  [i][d]
  __shared__ __hip_bfloat16 Bs[64][72];   // K or W tile [t][d]
  __shared__ __hip_bfloat16 Cs[64][72];   // AbT tile [j][t]
  __shared__ __hip_bfloat16 Ms[64][72];   // masked -qw [i][t]
  int ti = blockIdx.x;
  int it = 0, accum = 0;
  while (accum + it + 1 <= ti) { accum += it + 1; ++it; }
  const int jt = ti - accum;
  const int bh = blockIdx.y;
  const int tid = threadIdx.x, w = tid >> 6, lane = tid & 63;
  const int fr = lane & 15, kq = lane >> 4;
  const size_t hb = (size_t)bh * T_;

  stage64(qb + (hb + it * 64) * DH, DH, Qs, tid);
  stage64(kb + (hb + jt * 64) * DH, DH, Bs, tid);
  __syncthreads();

  const bf16x8 a0 = ldfrag(Qs, w, 0, fr, kq);
  const bf16x8 a1 = ldfrag(Qs, w, 1, fr, kq);

  f32x4 acc[4];
  const f32x4 zero = {0.f, 0.f, 0.f, 0.f};
#pragma unroll
  for (int nb = 0; nb < 4; ++nb) {
    acc[nb] = MFMA_BF16(a0, ldfrag(Bs, nb, 0, fr, kq), zero);
    acc[nb] = MFMA_BF16(a1, ldfrag(Bs, nb, 1, fr, kq), acc[nb]);
  }

  for (int c = jt; c <= it; ++c) {
    __syncthreads();
    stage64(wb + (hb + c * 64) * DH, DH, Bs, tid);
    stage64(abT + (hb + jt * 64) * T_ + c * 64, T_, Cs, tid);
    __syncthreads();
    f32x4 qw[4];
#pragma unroll
    for (int nb = 0; nb < 4; ++nb) {
      qw[nb] = MFMA_BF16(a0, ldfrag(Bs, nb, 0, fr, kq), zero);
      qw[nb] = MFMA_BF16(a1, ldfrag(Bs, nb, 1, fr, kq), qw[nb]);
    }
    const int row0 = w * 16 + kq * 4;
    const bool diag = (c == it);
#pragma unroll
    for (int nb = 0; nb < 4; ++nb) {
      int col = nb * 16 + fr;
#pragma unroll
      for (int reg = 0; reg < 4; ++reg) {
        float v = -qw[nb][reg];
        if (diag && col > row0 + reg) v = 0.f;
        Ms[row0 + reg][col] = __float2bfloat16(v);
      }
    }
    __syncthreads();
    const bf16x8 m0 = ldfrag(Ms, w, 0, fr, kq);
    const bf16x8 m1 = ldfrag(Ms, w, 1, fr, kq);
#pragma unroll
    for (int nb = 0; nb < 4; ++nb) {
      acc[nb] = MFMA_BF16(m0, ldfrag(Cs, nb, 0, fr, kq), acc[nb]);
      acc[nb] = MFMA_BF16(m1, ldfrag(Cs, nb, 1, fr, kq), acc[nb]);
    }
  }
#pragma unroll
  for (int nb = 0; nb < 4; ++nb) {
    int j = jt * 64 + nb * 16 + fr;
#pragma unroll
    for (int reg = 0; reg < 4; ++reg) {
      S[(hb + it * 64 + w * 16 + kq * 4 + reg) * T_ + j] = acc[nb][reg];
    }
  }
}

// ======================= softmax with gate-cumsum bias, causal =======================
__global__ __launch_bounds__(64) void softmax_k(float* __restrict__ S, const float* __restrict__ G) {
  int i = blockIdx.x, bh = blockIdx.y;
  int lane = threadIdx.x;
  const float Gi = G[(size_t)bh * T_ + i];
  float* row = S + ((size_t)bh * T_ + i) * T_;
  const float* Gb = G + (size_t)bh * T_;
  float l[8];
  float m = -3e38f;
#pragma unroll
  for (int c = 0; c < 8; ++c) {
    int j = lane + c * 64;
    if (j <= i) { float v = row[j] * 0.125f + Gi - Gb[j]; l[c] = v; m = fmaxf(m, v); }
    else l[c] = -3e38f;
  }
#pragma unroll
  for (int mm = 32; mm >= 1; mm >>= 1) m = fmaxf(m, __shfl_xor(m, mm));
  float ssum = 0.f;
#pragma unroll
  for (int c = 0; c < 8; ++c) {
    int j = lane + c * 64;
    float p = (j <= i) ? expf(l[c] - m) : 0.f;
    l[c] = p; ssum += p;
  }
#pragma unroll
  for (int mm = 32; mm >= 1; mm >>= 1) ssum += __shfl_xor(ssum, mm);
  float inv = 1.f / ssum;
#pragma unroll
  for (int c = 0; c < 8; ++c) row[lane + c * 64] = l[c] * inv;
}

// ======================= o = P @ V, output split to bf16 hi/lo =======================
__global__ __launch_bounds__(256) void pv_k(const float* __restrict__ P,
                                            const float* __restrict__ vT,
                                            __hip_bfloat16* __restrict__ ohi,
                                            __hip_bfloat16* __restrict__ olo) {
  int it = blockIdx.x, bh = blockIdx.y;
  int b = bh >> 4, h = bh & 15;
  __shared__ float Ps[64][68];
  __shared__ float Vs[64][68];
  const int tid = threadIdx.x;
  const int tm = (tid >> 4) << 2, tn = (tid & 15) << 2;
  float acc[4][4] = {};
  for (int c = 0; c <= it; ++c) {
    __syncthreads();
    for (int l = 0; l < 4; ++l) {
      int f = tid + l * 256;
      int r = f >> 4, c4 = (f & 15) << 2;
      *(float4*)&Ps[r][c4] = *(const float4*)&P[((size_t)bh * T_ + it * 64 + r) * T_ + c * 64 + c4];
      *(float4*)&Vs[r][c4] = *(const float4*)&vT[(((size_t)bh) * T_ + c * 64 + r) * DH + c4];
    }
    __syncthreads();
#pragma unroll
    for (int kk = 0; kk < 64; ++kk) {
      float a0 = Ps[tm + 0][kk], a1 = Ps[tm + 1][kk], a2 = Ps[tm + 2][kk], a3 = Ps[tm + 3][kk];
      float4 bvec = *(const float4*)&Vs[kk][tn];
      acc[0][0] += a0 * bvec.x; acc[0][1] += a0 * bvec.y; acc[0][2] += a0 * bvec.z; acc[0][3] += a0 * bvec.w;
      acc[1][0] += a1 * bvec.x; acc[1][1] += a1 * bvec.y; acc[1][2] += a1 * bvec.z; acc[1][3] += a1 * bvec.w;
      acc[2][0] += a2 * bvec.x; acc[2][1] += a2 * bvec.y; acc[2][2] += a2 * bvec.z; acc[2][3] += a2 * bvec.w;
      acc[3][0] += a3 * bvec.x; acc[3][1] += a3 * bvec.y; acc[3][2] += a3 * bvec.z; acc[3][3] += a3 * bvec.w;
    }
  }
#pragma unroll
  for (int ii = 0; ii < 4; ++ii) {
    int i = it * 64 + tm + ii;
#pragma unroll
    for (int jj = 0; jj < 4; ++jj) {
      size_t oi = ((size_t)(b * T_ + i)) * D_ + h * 64 + tn + jj;
      float v = acc[ii][jj];
      __hip_bfloat16 hv = __float2bfloat16(v);
      ohi[oi] = hv;
      olo[oi] = __float2bfloat16(v - __bfloat162float(hv));
    }
  }
}

// ======================= launch =======================
extern "C" void kernel_launch(void* const* d_in, const int* in_sizes, int n_in,
                              void* d_out, int out_size, void* d_ws, size_t ws_size,
                              hipStream_t stream) {
  (void)in_sizes; (void)n_in; (void)out_size; (void)ws_size;
  const float* x     = (const float*)d_in[0];
  const float* Wq    = (const float*)d_in[1];
  const float* Wk    = (const float*)d_in[2];
  const float* Wv    = (const float*)d_in[3];
  const float* Wo    = (const float*)d_in[4];
  const float* wA    = (const float*)d_in[5];
  const float* wB    = (const float*)d_in[6];
  const float* convw = (const float*)d_in[7];
  const float* bw    = (const float*)d_in[8];
  const float* gw    = (const float*)d_in[9];
  const float* gb    = (const float*)d_in[10];
  const float* qnw   = (const float*)d_in[11];
  const float* knw   = (const float*)d_in[12];

  const size_t N1 = (size_t)BT_ * D_;          // 1,048,576 elems
  const size_t NTT = (size_t)BH_ * T_ * T_;    // 8,388,608 elems
  float* ws = (float*)d_ws;
  float* q    = ws;                 // [BT,D] fp32
  float* k    = q   + N1;           // [BT,D] fp32
  float* vTb  = k   + N1;           // [BH,T,dh] fp32
  float* wTb  = vTb + N1;           // [BH,T,dh] fp32
  float* S    = wTb + N1;           // [BH,T,T] fp32
  float* wlow = S + NTT;            // [BT,R]
  float* beta = wlow + (size_t)BT_ * R_;
  float* G    = beta + (size_t)BH_ * T_;
  __hip_bfloat16* qb16  = (__hip_bfloat16*)(G + (size_t)BH_ * T_);
  __hip_bfloat16* kb16  = qb16 + N1;
  __hip_bfloat16* wb16  = kb16 + N1;
  __hip_bfloat16* abT   = wb16 + N1;            // [BH,T(j),T(t)] bf16
  __hip_bfloat16* linvb = abT + NTT;            // [BH,8,64,64] bf16
  __hip_bfloat16* xhi   = linvb + (size_t)BH_ * 8 * 4096;
  __hip_bfloat16* xlo   = xhi + N1;
  __hip_bfloat16* obhi  = xlo + N1;
  __hip_bfloat16* oblo  = obhi + N1;
  __hip_bfloat16* woThi = oblo + N1;
  __hip_bfloat16* woTlo = woThi + N1;
  // Wq/Wk/Wv transposed-split buffers alias S (S is written later in stream order)
  __hip_bfloat16* wqThi = (__hip_bfloat16*)S;
  __hip_bfloat16* wqTlo = wqThi + N1;
  __hip_bfloat16* wkThi = wqTlo + N1;
  __hip_bfloat16* wkTlo = wkThi + N1;
  __hip_bfloat16* wvThi = wkTlo + N1;
  __hip_bfloat16* wvTlo = wvThi + N1;

  dim3 g16(16, 16);
  split_f32<<<1024, 256, 0, stream>>>(x, xhi, xlo);
  splitT_k<<<g16, 256, 0, stream>>>(Wq, wqThi, wqTlo);
  splitT_k<<<g16, 256, 0, stream>>>(Wk, wkThi, wkTlo);
  splitT_k<<<g16, 256, 0, stream>>>(Wv, wvThi, wvTlo);
  splitT_k<<<g16, 256, 0, stream>>>(Wo, woThi, woTlo);
  gemm_split<0><<<g16, 256, 0, stream>>>(xhi, xlo, wqThi, wqTlo, q);
  gemm_split<0><<<g16, 256, 0, stream>>>(xhi, xlo, wkThi, wkTlo, k);
  gemm_split<1><<<g16, 256, 0, stream>>>(xhi, xlo, wvThi, wvTlo, vTb);
  proj_small<<<BT_, 64, 0, stream>>>(x, wA, bw, gw, gb, wlow, beta, G);
  cumsum_k<<<BH_, 512, 0, stream>>>(G);
  wdir_k<<<BT_, 1024, 0, stream>>>(wlow, wB, convw, wTb, wb16);
  rmsT_k<<<BT_, 1024, 0, stream>>>(q, k, qnw, knw, qb16, kb16);
  linv_k<<<dim3(8, BH_), 256, 0, stream>>>(wTb, beta, linvb);
  chain_k<<<dim3(8, BH_), 256, 0, stream>>>(kb16, wb16, linvb, beta, abT);
  s_mfma<<<dim3(36, BH_), 256, 0, stream>>>(qb16, kb16, wb16, abT, S);
  softmax_k<<<dim3(T_, BH_), 64, 0, stream>>>(S, G);
  pv_k<<<dim3(8, BH_), 256, 0, stream>>>(S, vTb, obhi, oblo);
  gemm_split<0><<<g16, 256, 0, stream>>>(obhi, oblo, woThi, woTlo, (float*)d_out);
}

// Round 4
// 237.662 us; speedup vs baseline: 7.8788x; 1.2089x over previous
//
#include <hip/hip_runtime.h>
#include <hip/hip_bf16.h>
#include <math.h>

#define B_ 2
#define T_ 512
#define D_ 1024
#define H_ 16
#define R_ 32
#define DH 64
#define BT_ (B_*T_)
#define BH_ (B_*H_)

typedef __attribute__((ext_vector_type(8))) short bf16x8;
typedef __attribute__((ext_vector_type(4))) short s16x4;
typedef __attribute__((ext_vector_type(4))) float f32x4;

#define MFMA_BF16(a, b, c) __builtin_amdgcn_mfma_f32_16x16x32_bf16(a, b, c, 0, 0, 0)

static __device__ __forceinline__ short bf16s(float v) {
  __hip_bfloat16 b = __float2bfloat16(v);
  return *reinterpret_cast<short*>(&b);
}

// ---- shared MFMA helpers (layout verified in R2) ----
__device__ __forceinline__ bf16x8 ldfrag(const __hip_bfloat16 s[][72], int b16, int kb, int fr, int kq) {
  return *(const bf16x8*)&s[b16 * 16 + fr][kb * 32 + kq * 8];
}
__device__ __forceinline__ void stage64(const __hip_bfloat16* __restrict__ g, int ldg,
                                        __hip_bfloat16 s[][72], int tid) {
#pragma unroll
  for (int l = 0; l < 2; ++l) {
    int f = tid + l * 256;
    int r = f >> 3, c = (f & 7) << 3;
    *(int4*)&s[r][c] = *(const int4*)&g[(size_t)r * ldg + c];
  }
}

// ======================= split fp32 -> bf16 hi/lo =======================
__global__ __launch_bounds__(256) void split_f32(const float* __restrict__ in,
                                                 __hip_bfloat16* __restrict__ hi,
                                                 __hip_bfloat16* __restrict__ lo) {
  int i4 = blockIdx.x * 256 + threadIdx.x;
  float4 v = ((const float4*)in)[i4];
  s16x4 ph, pl;
  float c[4] = {v.x, v.y, v.z, v.w};
#pragma unroll
  for (int u = 0; u < 4; ++u) {
    __hip_bfloat16 h = __float2bfloat16(c[u]);
    ph[u] = *reinterpret_cast<short*>(&h);
    pl[u] = bf16s(c[u] - __bfloat162float(h));
  }
  ((s16x4*)hi)[i4] = ph;
  ((s16x4*)lo)[i4] = pl;
}

// ======================= transpose + split weights: W[K][N] -> WT hi/lo [N][K] ============
__global__ __launch_bounds__(256) void splitT_k(const float* __restrict__ Wm,
                                                __hip_bfloat16* __restrict__ thi,
                                                __hip_bfloat16* __restrict__ tlo) {
  __shared__ float tile[64][65];
  const int bn = blockIdx.x * 64, bk = blockIdx.y * 64;
  const int tid = threadIdx.x;
#pragma unroll
  for (int l = 0; l < 4; ++l) {
    int f = tid + l * 256; int r = f >> 4, c = (f & 15) << 2;
    *(float4*)&tile[r][c] = *(const float4*)&Wm[(size_t)(bk + r) * D_ + bn + c];
  }
  __syncthreads();
#pragma unroll
  for (int l = 0; l < 4; ++l) {
    int f = tid + l * 256; int n = f >> 4, k0 = (f & 15) << 2;
    s16x4 ph, pl;
#pragma unroll
    for (int u = 0; u < 4; ++u) {
      float v = tile[k0 + u][n];
      __hip_bfloat16 h = __float2bfloat16(v);
      ph[u] = *reinterpret_cast<short*>(&h);
      pl[u] = bf16s(v - __bfloat162float(h));
    }
    *(s16x4*)&thi[(size_t)(bn + n) * D_ + bk + k0] = ph;
    *(s16x4*)&tlo[(size_t)(bn + n) * D_ + bk + k0] = pl;
  }
}

// ======================= concat+transpose+split small proj weights [wA|bw|gw] -> [64][D] ==
__global__ __launch_bounds__(256) void splitcat_k(const float* __restrict__ wA,
                                                  const float* __restrict__ bw,
                                                  const float* __restrict__ gw,
                                                  __hip_bfloat16* __restrict__ thi,
                                                  __hip_bfloat16* __restrict__ tlo) {
  int n = blockIdx.x;          // 0..63
  int tid = threadIdx.x;
  for (int k = tid; k < D_; k += 256) {
    float v;
    if (n < 32) v = wA[(size_t)k * R_ + n];
    else if (n < 48) v = bw[(size_t)k * H_ + (n - 32)];
    else v = gw[(size_t)k * H_ + (n - 48)];
    __hip_bfloat16 h = __float2bfloat16(v);
    thi[(size_t)n * D_ + k] = h;
    tlo[(size_t)n * D_ + k] = __float2bfloat16(v - __bfloat162float(h));
  }
}

// ======================= fp32-class GEMM via 3x bf16 MFMA =======================
// MODE 0: C[M,D] row-major fp32.  MODE 1: V scatter, transposed hi/lo bf16 [B,H,dh,T].
// MODE 2: C[M,64] row-major fp32 (ycat; grid.x must be 1).
template<int MODE>
__global__ __launch_bounds__(256) void gemm_split(const __hip_bfloat16* __restrict__ ah,
                                                  const __hip_bfloat16* __restrict__ al,
                                                  const __hip_bfloat16* __restrict__ bh,
                                                  const __hip_bfloat16* __restrict__ bl,
                                                  float* __restrict__ C,
                                                  __hip_bfloat16* __restrict__ Chi,
                                                  __hip_bfloat16* __restrict__ Clo) {
  __shared__ __hip_bfloat16 Ah[64][72], Al[64][72], Bh[64][72], Bl[64][72];
  const int bm = blockIdx.y * 64, bn = blockIdx.x * 64;
  const int tid = threadIdx.x, w = tid >> 6, lane = tid & 63;
  const int fr = lane & 15, kq = lane >> 4;
  const f32x4 zf = {0.f, 0.f, 0.f, 0.f};
  f32x4 acc[4] = {zf, zf, zf, zf};
  for (int k0 = 0; k0 < D_; k0 += 64) {
    __syncthreads();
    stage64(ah + (size_t)bm * D_ + k0, D_, Ah, tid);
    stage64(al + (size_t)bm * D_ + k0, D_, Al, tid);
    stage64(bh + (size_t)bn * D_ + k0, D_, Bh, tid);
    stage64(bl + (size_t)bn * D_ + k0, D_, Bl, tid);
    __syncthreads();
    bf16x8 ah0 = ldfrag(Ah, w, 0, fr, kq), ah1 = ldfrag(Ah, w, 1, fr, kq);
    bf16x8 al0 = ldfrag(Al, w, 0, fr, kq), al1 = ldfrag(Al, w, 1, fr, kq);
#pragma unroll
    for (int nb = 0; nb < 4; ++nb) {
      bf16x8 b0 = ldfrag(Bh, nb, 0, fr, kq), b1 = ldfrag(Bh, nb, 1, fr, kq);
      bf16x8 c0 = ldfrag(Bl, nb, 0, fr, kq), c1 = ldfrag(Bl, nb, 1, fr, kq);
      acc[nb] = MFMA_BF16(ah0, b0, acc[nb]); acc[nb] = MFMA_BF16(ah1, b1, acc[nb]);
      acc[nb] = MFMA_BF16(ah0, c0, acc[nb]); acc[nb] = MFMA_BF16(ah1, c1, acc[nb]);
      acc[nb] = MFMA_BF16(al0, b0, acc[nb]); acc[nb] = MFMA_BF16(al1, b1, acc[nb]);
    }
  }
#pragma unroll
  for (int nb = 0; nb < 4; ++nb) {
    int n = bn + nb * 16 + fr;
#pragma unroll
    for (int reg = 0; reg < 4; ++reg) {
      int m = bm + w * 16 + kq * 4 + reg;
      float v = acc[nb][reg];
      if (MODE == 0) {
        C[(size_t)m * D_ + n] = v;
      } else if (MODE == 1) {
        int b = m >> 9, t = m & 511, h = n >> 6, dd = n & 63;
        size_t oi = (((size_t)(b * H_ + h)) * DH + dd) * T_ + t;
        __hip_bfloat16 hv = __float2bfloat16(v);
        Chi[oi] = hv;
        Clo[oi] = __float2bfloat16(v - __bfloat162float(hv));
      } else {
        C[(size_t)m * 64 + n] = v;
      }
    }
  }
}

// ======================= gates: beta, logsigmoid + cumsum =======================
__global__ __launch_bounds__(512) void gate_cumsum(const float* __restrict__ ycat,
                                                   const float* __restrict__ gb,
                                                   float* __restrict__ beta,
                                                   float* __restrict__ G) {
  __shared__ float s[T_];
  int bh = blockIdx.x, b = bh >> 4, h = bh & 15, t = threadIdx.x;
  int bt = b * T_ + t;
  float by = ycat[(size_t)bt * 64 + 32 + h];
  beta[(size_t)bh * T_ + t] = 2.f / (1.f + expf(-by));
  float gy = ycat[(size_t)bt * 64 + 48 + h] + gb[h];
  s[t] = fminf(gy, 0.f) - log1pf(expf(-fabsf(gy)));
  __syncthreads();
  for (int off = 1; off < T_; off <<= 1) {
    float v = (t >= off) ? s[t - off] : 0.f;
    __syncthreads();
    s[t] += v;
    __syncthreads();
  }
  G[(size_t)bh * T_ + t] = s[t];
}

// ======================= w: low-rank expand + conv3 + silu + unit-normalize ===========
__global__ __launch_bounds__(1024) void wdir_k(const float* __restrict__ ycat,
                                               const float* __restrict__ wB,
                                               const float* __restrict__ convw,
                                               float* __restrict__ wT,
                                               __hip_bfloat16* __restrict__ wb16) {
  int bt = blockIdx.x, b = bt / T_, t = bt - b * T_;
  __shared__ float wl[3][R_];
  int tid = threadIdx.x;
  if (tid < 3 * R_) {
    int row = tid / R_, r = tid - row * R_;
    int ts = t - row;
    wl[row][r] = (ts >= 0) ? ycat[(size_t)(b * T_ + ts) * 64 + r] : 0.f;
  }
  __syncthreads();
  float f0 = 0.f, f1 = 0.f, f2 = 0.f;
  for (int r = 0; r < R_; ++r) {
    float wb = wB[(size_t)r * D_ + tid];
    f0 += wl[0][r] * wb; f1 += wl[1][r] * wb; f2 += wl[2][r] * wb;
  }
  float y = f2 * convw[tid * 3 + 0] + f1 * convw[tid * 3 + 1] + f0 * convw[tid * 3 + 2];
  float s = y / (1.f + expf(-y));                       // silu
  float ss = s * s;
#pragma unroll
  for (int m = 32; m >= 1; m >>= 1) ss += __shfl_xor(ss, m);
  float outv = s * rsqrtf(ss + 1e-12f);
  int h = tid >> 6, dd = tid & 63;
  size_t o = (((size_t)(b * H_ + h)) * T_ + t) * DH + dd;
  wT[o] = outv;
  wb16[o] = __float2bfloat16(outv);
}

// ======================= rmsnorm q,k -> bf16 [B,H,T,dh] =======================
__global__ __launch_bounds__(1024) void rmsT_k(const float* __restrict__ q,
                                               const float* __restrict__ k,
                                               const float* __restrict__ qnw,
                                               const float* __restrict__ knw,
                                               __hip_bfloat16* __restrict__ qb16,
                                               __hip_bfloat16* __restrict__ kb16) {
  int bt = blockIdx.x, b = bt / T_, t = bt - b * T_;
  int tid = threadIdx.x, h = tid >> 6, dd = tid & 63;
  float qv = q[(size_t)bt * D_ + tid];
  float kv = k[(size_t)bt * D_ + tid];
  float sq = qv * qv, sk = kv * kv;
#pragma unroll
  for (int m = 32; m >= 1; m >>= 1) { sq += __shfl_xor(sq, m); sk += __shfl_xor(sk, m); }
  float qs = qv * rsqrtf(sq * (1.f / DH) + 1e-5f) * qnw[dd];
  float ks = kv * rsqrtf(sk * (1.f / DH) + 1e-5f) * knw[dd];
  size_t o = (((size_t)(b * H_ + h)) * T_ + t) * DH + dd;
  qb16[o] = __float2bfloat16(qs);
  kb16[o] = __float2bfloat16(ks);
}

// ======================= per-block unit-lower-triangular inverse =======================
__global__ __launch_bounds__(256) void linv_k(const float* __restrict__ wT,
                                              const float* __restrict__ beta,
                                              __hip_bfloat16* __restrict__ linv) {
  __shared__ float Wsh[64][68];
  __shared__ float Csh[64][65];
  __shared__ float Li[64][68];
  __shared__ float bI[64];
  const int I = blockIdx.x, bhx = blockIdx.y;
  const int tid = threadIdx.x;
#pragma unroll
  for (int l = 0; l < 4; ++l) {
    int f = tid + l * 256; int r = f >> 4, c = (f & 15) << 2;
    *(float4*)&Wsh[r][c] = *(const float4*)&wT[((size_t)bhx * T_ + I * 64 + r) * DH + c];
  }
  if (tid < 64) bI[tid] = beta[(size_t)bhx * T_ + I * 64 + tid];
#pragma unroll
  for (int l = 0; l < 16; ++l) {
    int e = tid + l * 256; int r = e >> 6, c = e & 63;
    Li[r][c] = (r == c) ? 1.f : 0.f;
  }
  __syncthreads();
  const int tm = (tid >> 4) << 2, tn = (tid & 15) << 2;
  float cc[4][4] = {};
  for (int dd = 0; dd < 64; ++dd) {
    float a0 = Wsh[tm + 0][dd], a1 = Wsh[tm + 1][dd], a2 = Wsh[tm + 2][dd], a3 = Wsh[tm + 3][dd];
    float b0 = Wsh[tn + 0][dd], b1 = Wsh[tn + 1][dd], b2 = Wsh[tn + 2][dd], b3 = Wsh[tn + 3][dd];
    cc[0][0] += a0 * b0; cc[0][1] += a0 * b1; cc[0][2] += a0 * b2; cc[0][3] += a0 * b3;
    cc[1][0] += a1 * b0; cc[1][1] += a1 * b1; cc[1][2] += a1 * b2; cc[1][3] += a1 * b3;
    cc[2][0] += a2 * b0; cc[2][1] += a2 * b1; cc[2][2] += a2 * b2; cc[2][3] += a2 * b3;
    cc[3][0] += a3 * b0; cc[3][1] += a3 * b1; cc[3][2] += a3 * b2; cc[3][3] += a3 * b3;
  }
#pragma unroll
  for (int ii = 0; ii < 4; ++ii)
#pragma unroll
    for (int jj = 0; jj < 4; ++jj)
      Csh[tm + ii][tn + jj] = (tm + ii > tn + jj) ? cc[ii][jj] * bI[tn + jj] : 0.f;
  __syncthreads();
  const int sL = tid & 63, g = tid >> 6;
  for (int r = 0; r < 63; ++r) {
    float lr = Li[r][sL];
    for (int r2 = r + 1 + g; r2 < 64; r2 += 4)
      Li[r2][sL] -= Csh[r2][r] * lr;
    __syncthreads();
  }
#pragma unroll
  for (int l = 0; l < 4; ++l) {
    int f = tid + l * 256; int r = f >> 4, c0 = (f & 15) << 2;
    s16x4 p;
    p.x = bf16s(Li[r][c0 + 0]); p.y = bf16s(Li[r][c0 + 1]);
    p.z = bf16s(Li[r][c0 + 2]); p.w = bf16s(Li[r][c0 + 3]);
    *(s16x4*)&linv[((size_t)(bhx * 8 + I)) * 4096 + r * 64 + c0] = p;
  }
}

// ======================= WY chain: per column-chunk, MFMA recurrence =======================
__global__ __launch_bounds__(256) void chain_k(const __hip_bfloat16* __restrict__ kb,
                                               const __hip_bfloat16* __restrict__ wb,
                                               const __hip_bfloat16* __restrict__ linv,
                                               const float* __restrict__ beta,
                                               __hip_bfloat16* __restrict__ abT) {
  __shared__ __hip_bfloat16 Kb[64][72];   // [j][d]
  __shared__ __hip_bfloat16 Ws[64][72];   // [t][d]
  __shared__ __hip_bfloat16 WsT[64][72];  // [d][t]
  __shared__ __hip_bfloat16 Ls[64][72];   // [t][s]
  __shared__ __hip_bfloat16 Mhi[64][72];  // [j][d] = -M hi
  __shared__ __hip_bfloat16 Mlo[64][72];  // [j][d] = -M lo
  __shared__ __hip_bfloat16 Ps[64][72];   // [j][t] PT, then reused as X
  __shared__ float bI[64];
  const int ch = blockIdx.x, bhx = blockIdx.y;
  const int tid = threadIdx.x, w = tid >> 6, lane = tid & 63;
  const int fr = lane & 15, kq = lane >> 4;
  const size_t hb = (size_t)bhx * T_;
  const f32x4 zf = {0.f, 0.f, 0.f, 0.f};

  stage64(kb + (hb + ch * 64) * DH, DH, Kb, tid);
  for (int f = tid; f < 576; f += 256) {
    ((int4*)Mhi)[f] = make_int4(0, 0, 0, 0);
    ((int4*)Mlo)[f] = make_int4(0, 0, 0, 0);
  }
  f32x4 macc[4] = {zf, zf, zf, zf};

  for (int I = ch; I < 8; ++I) {
    __syncthreads();                                           // B1
    stage64(wb + (hb + I * 64) * DH, DH, Ws, tid);
    stage64(linv + ((size_t)(bhx * 8 + I)) * 4096, 64, Ls, tid);
    if (tid < 64) bI[tid] = beta[hb + I * 64 + tid];
    const int jr = w * 16 + kq * 4;
    if (I > ch) {
#pragma unroll
      for (int nb = 0; nb < 4; ++nb) {
        int d = nb * 16 + fr;
#pragma unroll
        for (int reg = 0; reg < 4; ++reg) {
          float m = -macc[nb][reg];
          __hip_bfloat16 h = __float2bfloat16(m);
          Mhi[jr + reg][d] = h;
          Mlo[jr + reg][d] = __float2bfloat16(m - __bfloat162float(h));
        }
      }
    }
    __syncthreads();                                           // B2
#pragma unroll
    for (int l = 0; l < 16; ++l) {
      int e = tid + l * 256;
      int t = e >> 6, d = e & 63;
      WsT[d][t] = Ws[t][d];
    }
    bf16x8 kb0 = ldfrag(Kb, w, 0, fr, kq), kb1 = ldfrag(Kb, w, 1, fr, kq);
    f32x4 pt[4];
#pragma unroll
    for (int nb = 0; nb < 4; ++nb) {
      bf16x8 b0 = ldfrag(Ws, nb, 0, fr, kq), b1 = ldfrag(Ws, nb, 1, fr, kq);
      pt[nb] = MFMA_BF16(kb0, b0, zf);
      pt[nb] = MFMA_BF16(kb1, b1, pt[nb]);
      if (I > ch) {
        bf16x8 mh0 = ldfrag(Mhi, w, 0, fr, kq), mh1 = ldfrag(Mhi, w, 1, fr, kq);
        bf16x8 ml0 = ldfrag(Mlo, w, 0, fr, kq), ml1 = ldfrag(Mlo, w, 1, fr, kq);
        pt[nb] = MFMA_BF16(mh0, b0, pt[nb]); pt[nb] = MFMA_BF16(mh1, b1, pt[nb]);
        pt[nb] = MFMA_BF16(ml0, b0, pt[nb]); pt[nb] = MFMA_BF16(ml1, b1, pt[nb]);
      }
    }
#pragma unroll
    for (int nb = 0; nb < 4; ++nb) {
      int t = nb * 16 + fr;
#pragma unroll
      for (int reg = 0; reg < 4; ++reg) {
        float v = pt[nb][reg];
        if (I == ch && t <= jr + reg) v = 0.f;
        Ps[jr + reg][t] = __float2bfloat16(v);
      }
    }
    __syncthreads();                                           // B3
    bf16x8 la0 = ldfrag(Ls, w, 0, fr, kq), la1 = ldfrag(Ls, w, 1, fr, kq);
    f32x4 av[4];
#pragma unroll
    for (int nb = 0; nb < 4; ++nb) {
      bf16x8 p0 = ldfrag(Ps, nb, 0, fr, kq), p1 = ldfrag(Ps, nb, 1, fr, kq);
      av[nb] = MFMA_BF16(la0, p0, zf);
      av[nb] = MFMA_BF16(la1, p1, av[nb]);
    }
    __syncthreads();                                           // B4
    const int tr = w * 16 + kq * 4;
#pragma unroll
    for (int nb = 0; nb < 4; ++nb) {
      s16x4 p;
      p.x = bf16s(bI[tr + 0] * av[nb][0]);
      p.y = bf16s(bI[tr + 1] * av[nb][1]);
      p.z = bf16s(bI[tr + 2] * av[nb][2]);
      p.w = bf16s(bI[tr + 3] * av[nb][3]);
      *(s16x4*)&Ps[nb * 16 + fr][tr] = p;
    }
    __syncthreads();                                           // B5
#pragma unroll
    for (int l = 0; l < 2; ++l) {
      int f = tid + l * 256;
      int r = f >> 3, c = (f & 7) << 3;
      *(int4*)&abT[(hb + ch * 64 + r) * T_ + I * 64 + c] = *(const int4*)&Ps[r][c];
    }
    bf16x8 xa0 = ldfrag(Ps, w, 0, fr, kq), xa1 = ldfrag(Ps, w, 1, fr, kq);
#pragma unroll
    for (int nb = 0; nb < 4; ++nb) {
      bf16x8 wt0 = ldfrag(WsT, nb, 0, fr, kq), wt1 = ldfrag(WsT, nb, 1, fr, kq);
      macc[nb] = MFMA_BF16(xa0, wt0, macc[nb]);
      macc[nb] = MFMA_BF16(xa1, wt1, macc[nb]);
    }
  }
}

// ======================= S via MFMA: S = Q K^T - tril(Q W^T) @ (beta A) =======================
__global__ __launch_bounds__(256) void s_mfma(const __hip_bfloat16* __restrict__ qb,
                                              const __hip_bfloat16* __restrict__ kb,
                                              const __hip_bfloat16* __restrict__ wb,
                                              const __hip_bfloat16* __restrict__ abT,
                                              float* __restrict__ S) {
  __shared__ __hip_bfloat16 Qs[64][72];
  __shared__ __hip_bfloat16 Bs[64][72];
  __shared__ __hip_bfloat16 Cs[64][72];
  __shared__ __hip_bfloat16 Ms[64][72];
  int ti = blockIdx.x;
  int it = 0, accum = 0;
  while (accum + it + 1 <= ti) { accum += it + 1; ++it; }
  const int jt = ti - accum;
  const int bh = blockIdx.y;
  const int tid = threadIdx.x, w = tid >> 6, lane = tid & 63;
  const int fr = lane & 15, kq = lane >> 4;
  const size_t hb = (size_t)bh * T_;

  stage64(qb + (hb + it * 64) * DH, DH, Qs, tid);
  stage64(kb + (hb + jt * 64) * DH, DH, Bs, tid);
  __syncthreads();

  const bf16x8 a0 = ldfrag(Qs, w, 0, fr, kq);
  const bf16x8 a1 = ldfrag(Qs, w, 1, fr, kq);

  f32x4 acc[4];
  const f32x4 zero = {0.f, 0.f, 0.f, 0.f};
#pragma unroll
  for (int nb = 0; nb < 4; ++nb) {
    acc[nb] = MFMA_BF16(a0, ldfrag(Bs, nb, 0, fr, kq), zero);
    acc[nb] = MFMA_BF16(a1, ldfrag(Bs, nb, 1, fr, kq), acc[nb]);
  }

  for (int c = jt; c <= it; ++c) {
    __syncthreads();
    stage64(wb + (hb + c * 64) * DH, DH, Bs, tid);
    stage64(abT + (hb + jt * 64) * T_ + c * 64, T_, Cs, tid);
    __syncthreads();
    f32x4 qw[4];
#pragma unroll
    for (int nb = 0; nb < 4; ++nb) {
      qw[nb] = MFMA_BF16(a0, ldfrag(Bs, nb, 0, fr, kq), zero);
      qw[nb] = MFMA_BF16(a1, ldfrag(Bs, nb, 1, fr, kq), qw[nb]);
    }
    const int row0 = w * 16 + kq * 4;
    const bool diag = (c == it);
#pragma unroll
    for (int nb = 0; nb < 4; ++nb) {
      int col = nb * 16 + fr;
#pragma unroll
      for (int reg = 0; reg < 4; ++reg) {
        float v = -qw[nb][reg];
        if (diag && col > row0 + reg) v = 0.f;
        Ms[row0 + reg][col] = __float2bfloat16(v);
      }
    }
    __syncthreads();
    const bf16x8 m0 = ldfrag(Ms, w, 0, fr, kq);
    const bf16x8 m1 = ldfrag(Ms, w, 1, fr, kq);
#pragma unroll
    for (int nb = 0; nb < 4; ++nb) {
      acc[nb] = MFMA_BF16(m0, ldfrag(Cs, nb, 0, fr, kq), acc[nb]);
      acc[nb] = MFMA_BF16(m1, ldfrag(Cs, nb, 1, fr, kq), acc[nb]);
    }
  }
#pragma unroll
  for (int nb = 0; nb < 4; ++nb) {
    int j = jt * 64 + nb * 16 + fr;
#pragma unroll
    for (int reg = 0; reg < 4; ++reg) {
      S[(hb + it * 64 + w * 16 + kq * 4 + reg) * T_ + j] = acc[nb][reg];
    }
  }
}

// ======================= softmax, causal, P written bf16 in place =======================
// One wave per row; all reads of the fp32 row precede the (aliasing) bf16 writes.
__global__ __launch_bounds__(64) void softmax_k(float* __restrict__ S, const float* __restrict__ G) {
  int i = blockIdx.x, bh = blockIdx.y;
  int lane = threadIdx.x;
  const float Gi = G[(size_t)bh * T_ + i];
  float* row = S + ((size_t)bh * T_ + i) * T_;
  const float* Gb = G + (size_t)bh * T_;
  float l[8];
  float m = -3e38f;
#pragma unroll
  for (int c = 0; c < 8; ++c) {
    int j = lane + c * 64;
    if (j <= i) { float v = row[j] * 0.125f + Gi - Gb[j]; l[c] = v; m = fmaxf(m, v); }
    else l[c] = -3e38f;
  }
#pragma unroll
  for (int mm = 32; mm >= 1; mm >>= 1) m = fmaxf(m, __shfl_xor(m, mm));
  float ssum = 0.f;
#pragma unroll
  for (int c = 0; c < 8; ++c) {
    int j = lane + c * 64;
    float p = (j <= i) ? expf(l[c] - m) : 0.f;
    l[c] = p; ssum += p;
  }
#pragma unroll
  for (int mm = 32; mm >= 1; mm >>= 1) ssum += __shfl_xor(ssum, mm);
  float inv = 1.f / ssum;
  __hip_bfloat16* prow = (__hip_bfloat16*)row;
#pragma unroll
  for (int c = 0; c < 8; ++c) prow[lane + c * 64] = __float2bfloat16(l[c] * inv);
}

// ======================= o = P @ V via MFMA (P bf16, V hi/lo bf16 transposed) ==========
__global__ __launch_bounds__(256) void pv_mfma(const __hip_bfloat16* __restrict__ pb,  // ld 2*T_
                                               const __hip_bfloat16* __restrict__ vhi, // [BH,dh,T]
                                               const __hip_bfloat16* __restrict__ vlo,
                                               __hip_bfloat16* __restrict__ ohi,
                                               __hip_bfloat16* __restrict__ olo) {
  __shared__ __hip_bfloat16 Ps[64][72];   // [i][t]
  __shared__ __hip_bfloat16 Vh[64][72];   // [dd][t]
  __shared__ __hip_bfloat16 Vl[64][72];   // [dd][t]
  const int it = blockIdx.x, bh = blockIdx.y;
  const int b = bh >> 4, h = bh & 15;
  const int tid = threadIdx.x, w = tid >> 6, lane = tid & 63;
  const int fr = lane & 15, kq = lane >> 4;
  const f32x4 zf = {0.f, 0.f, 0.f, 0.f};
  f32x4 acc[4] = {zf, zf, zf, zf};
  for (int c = 0; c <= it; ++c) {
    __syncthreads();
    stage64(pb + ((size_t)bh * T_ + it * 64) * (2 * T_) + c * 64, 2 * T_, Ps, tid);
    stage64(vhi + ((size_t)bh * DH) * T_ + c * 64, T_, Vh, tid);
    stage64(vlo + ((size_t)bh * DH) * T_ + c * 64, T_, Vl, tid);
    __syncthreads();
    bf16x8 p0 = ldfrag(Ps, w, 0, fr, kq), p1 = ldfrag(Ps, w, 1, fr, kq);
#pragma unroll
    for (int nb = 0; nb < 4; ++nb) {
      acc[nb] = MFMA_BF16(p0, ldfrag(Vh, nb, 0, fr, kq), acc[nb]);
      acc[nb] = MFMA_BF16(p1, ldfrag(Vh, nb, 1, fr, kq), acc[nb]);
      acc[nb] = MFMA_BF16(p0, ldfrag(Vl, nb, 0, fr, kq), acc[nb]);
      acc[nb] = MFMA_BF16(p1, ldfrag(Vl, nb, 1, fr, kq), acc[nb]);
    }
  }
#pragma unroll
  for (int nb = 0; nb < 4; ++nb) {
    int dd = nb * 16 + fr;
#pragma unroll
    for (int reg = 0; reg < 4; ++reg) {
      int i = it * 64 + w * 16 + kq * 4 + reg;
      size_t oi = ((size_t)(b * T_ + i)) * D_ + h * 64 + dd;
      float v = acc[nb][reg];
      __hip_bfloat16 hv = __float2bfloat16(v);
      ohi[oi] = hv;
      olo[oi] = __float2bfloat16(v - __bfloat162float(hv));
    }
  }
}

// ======================= launch =======================
extern "C" void kernel_launch(void* const* d_in, const int* in_sizes, int n_in,
                              void* d_out, int out_size, void* d_ws, size_t ws_size,
                              hipStream_t stream) {
  (void)in_sizes; (void)n_in; (void)out_size; (void)ws_size;
  const float* x     = (const float*)d_in[0];
  const float* Wq    = (const float*)d_in[1];
  const float* Wk    = (const float*)d_in[2];
  const float* Wv    = (const float*)d_in[3];
  const float* Wo    = (const float*)d_in[4];
  const float* wA    = (const float*)d_in[5];
  const float* wB    = (const float*)d_in[6];
  const float* convw = (const float*)d_in[7];
  const float* bw    = (const float*)d_in[8];
  const float* gw    = (const float*)d_in[9];
  const float* gb    = (const float*)d_in[10];
  const float* qnw   = (const float*)d_in[11];
  const float* knw   = (const float*)d_in[12];

  const size_t N1 = (size_t)BT_ * D_;          // 1,048,576
  const size_t NTT = (size_t)BH_ * T_ * T_;    // 8,388,608
  float* ws = (float*)d_ws;
  float* q    = ws;                 // [BT,D] fp32
  float* k    = q   + N1;           // [BT,D] fp32
  float* wTb  = k   + N1;           // [BH,T,dh] fp32
  float* ycat = wTb + N1;           // [BT,64] fp32
  float* S    = ycat + (size_t)BT_ * 64;  // [BH,T,T] fp32 (P bf16 aliases rows)
  float* beta = S + NTT;
  float* G    = beta + (size_t)BH_ * T_;
  __hip_bfloat16* qb16  = (__hip_bfloat16*)(G + (size_t)BH_ * T_);
  __hip_bfloat16* kb16  = qb16 + N1;
  __hip_bfloat16* wb16  = kb16 + N1;
  __hip_bfloat16* abT   = wb16 + N1;            // [BH,T(j),T(t)] bf16
  __hip_bfloat16* linvb = abT + NTT;            // [BH,8,64,64] bf16
  __hip_bfloat16* xhi   = linvb + (size_t)BH_ * 8 * 4096;
  __hip_bfloat16* xlo   = xhi + N1;
  __hip_bfloat16* obhi  = xlo + N1;
  __hip_bfloat16* oblo  = obhi + N1;
  __hip_bfloat16* woThi = oblo + N1;
  __hip_bfloat16* woTlo = woThi + N1;
  __hip_bfloat16* vhi   = woTlo + N1;           // [BH,dh,T] bf16
  __hip_bfloat16* vlo   = vhi + N1;
  // Wq/Wk/Wv/Wcat transposed-split buffers alias S (S written later in stream order)
  __hip_bfloat16* wqThi = (__hip_bfloat16*)S;
  __hip_bfloat16* wqTlo = wqThi + N1;
  __hip_bfloat16* wkThi = wqTlo + N1;
  __hip_bfloat16* wkTlo = wkThi + N1;
  __hip_bfloat16* wvThi = wkTlo + N1;
  __hip_bfloat16* wvTlo = wvThi + N1;
  __hip_bfloat16* wcThi = wvTlo + N1;           // [64][D]
  __hip_bfloat16* wcTlo = wcThi + (size_t)64 * D_;

  dim3 g16(16, 16);
  split_f32<<<1024, 256, 0, stream>>>(x, xhi, xlo);
  splitT_k<<<g16, 256, 0, stream>>>(Wq, wqThi, wqTlo);
  splitT_k<<<g16, 256, 0, stream>>>(Wk, wkThi, wkTlo);
  splitT_k<<<g16, 256, 0, stream>>>(Wv, wvThi, wvTlo);
  splitT_k<<<g16, 256, 0, stream>>>(Wo, woThi, woTlo);
  splitcat_k<<<64, 256, 0, stream>>>(wA, bw, gw, wcThi, wcTlo);
  gemm_split<0><<<g16, 256, 0, stream>>>(xhi, xlo, wqThi, wqTlo, q, nullptr, nullptr);
  gemm_split<0><<<g16, 256, 0, stream>>>(xhi, xlo, wkThi, wkTlo, k, nullptr, nullptr);
  gemm_split<1><<<g16, 256, 0, stream>>>(xhi, xlo, wvThi, wvTlo, nullptr, vhi, vlo);
  gemm_split<2><<<dim3(1, 16), 256, 0, stream>>>(xhi, xlo, wcThi, wcTlo, ycat, nullptr, nullptr);
  gate_cumsum<<<BH_, 512, 0, stream>>>(ycat, gb, beta, G);
  wdir_k<<<BT_, 1024, 0, stream>>>(ycat, wB, convw, wTb, wb16);
  rmsT_k<<<BT_, 1024, 0, stream>>>(q, k, qnw, knw, qb16, kb16);
  linv_k<<<dim3(8, BH_), 256, 0, stream>>>(wTb, beta, linvb);
  chain_k<<<dim3(8, BH_), 256, 0, stream>>>(kb16, wb16, linvb, beta, abT);
  s_mfma<<<dim3(36, BH_), 256, 0, stream>>>(qb16, kb16, wb16, abT, S);
  softmax_k<<<dim3(T_, BH_), 64, 0, stream>>>(S, G);
  pv_mfma<<<dim3(8, BH_), 256, 0, stream>>>((const __hip_bfloat16*)S, vhi, vlo, obhi, oblo);
  gemm_split<0><<<g16, 256, 0, stream>>>(obhi, oblo, woThi, woTlo, (float*)d_out, nullptr, nullptr);
}